// Round 4
// baseline (3295.589 us; speedup 1.0000x reference)
//
#include <hip/hip_runtime.h>
#include <hip/hip_bf16.h>

#define BATCH 8
#define CHN   192      // d_model
#define LEN   4096     // H*W tokens
#define DIP   902      // in_proj out dim
#define DI    384      // d_inner
#define NHEAD 6
#define HDIM  64
#define DST   64       // d_state
#define NCHK  16       // chunks (LEN/256)

// ---------------- K1: transposing LayerNorm1: x (g,192,L) f32 -> h1 (g,L,192) f32
__global__ __launch_bounds__(256) void k_ln1(const float* __restrict__ x,
    const float* __restrict__ w, const float* __restrict__ b, float* __restrict__ h1) {
  __shared__ float s[192][33];
  __shared__ float red[2][32][8];
  __shared__ float mu_s[32], rs_s[32];
  int bb = blockIdx.y;
  int t0 = blockIdx.x * 32;
  int tid = threadIdx.x;
  for (int i = 0; i < 24; ++i) {
    int idx = tid + i * 256;            // 192*32 = 6144
    int c = idx >> 5, tt = idx & 31;
    s[c][tt] = x[((size_t)bb * CHN + c) * LEN + t0 + tt];
  }
  __syncthreads();
  int tok = tid & 31, part = tid >> 5;
  float sum = 0.f, sq = 0.f;
  for (int c = part * 24; c < part * 24 + 24; ++c) { float v = s[c][tok]; sum += v; sq += v * v; }
  red[0][tok][part] = sum; red[1][tok][part] = sq;
  __syncthreads();
  if (tid < 32) {
    float su = 0.f, qq = 0.f;
    for (int p = 0; p < 8; ++p) { su += red[0][tid][p]; qq += red[1][tid][p]; }
    float mu = su / 192.f;
    float var = qq / 192.f - mu * mu;
    mu_s[tid] = mu; rs_s[tid] = rsqrtf(var + 1e-5f);
  }
  __syncthreads();
  for (int i = 0; i < 24; ++i) {
    int idx = tid + i * 256;
    int c = idx % 192, tt = idx / 192;
    float v = (s[c][tt] - mu_s[tt]) * rs_s[tt] * w[c] + b[c];
    h1[((size_t)bb * LEN + t0 + tt) * CHN + c] = v;
  }
}

// ---------------- K2: u[b,l,c2] = h1_flat[b][c2*LEN + l]  (flat reinterpretation transpose)
__global__ void k_make_u(const float* __restrict__ h1, float* __restrict__ U) {
  __shared__ float s[32][33];
  int bb = blockIdx.z;
  int c0 = blockIdx.y * 32;
  int l0 = blockIdx.x * 32;
  int tx = threadIdx.x, ty = threadIdx.y;
  const float* src = h1 + (size_t)bb * (CHN * LEN);
  for (int i = 0; i < 4; ++i)
    s[ty + i * 8][tx] = src[(size_t)(c0 + ty + i * 8) * LEN + l0 + tx];
  __syncthreads();
  float* dst = U + (size_t)bb * (CHN * LEN);
  for (int i = 0; i < 4; ++i)
    dst[(size_t)(l0 + ty + i * 8) * CHN + c0 + tx] = s[tx][ty + i * 8];
}

// ---------------- generic tiled GEMM: C[M,N] = A[M,K](f32) @ W[N,K]^T(f32), epilogues
// EPI 0: none ; 1: +bias then exact gelu ; 2: +bias
template <int EPI>
__global__ __launch_bounds__(256) void gemm_aw(const float* __restrict__ A,
    const float* __restrict__ W, const float* __restrict__ bias,
    float* __restrict__ C, int M, int N, int K) {
  __shared__ float As[32][65];
  __shared__ float Ws[32][65];
  int m0 = blockIdx.y * 64, n0 = blockIdx.x * 64;
  int tid = threadIdx.x;
  int tx = tid & 15, ty = tid >> 4;
  float acc[4][4] = {};
  for (int k0 = 0; k0 < K; k0 += 32) {
    for (int i = 0; i < 8; ++i) {
      int idx = tid + i * 256;
      int r = idx >> 5, c = idx & 31;
      As[c][r] = A[(size_t)(m0 + r) * K + k0 + c];
    }
    for (int i = 0; i < 8; ++i) {
      int idx = tid + i * 256;
      int r = idx >> 5, c = idx & 31;
      int n = n0 + r;
      Ws[c][r] = (n < N) ? W[(size_t)n * K + k0 + c] : 0.f;
    }
    __syncthreads();
#pragma unroll
    for (int kk = 0; kk < 32; ++kk) {
      float a[4], bb_[4];
#pragma unroll
      for (int i = 0; i < 4; ++i) a[i] = As[kk][ty * 4 + i];
#pragma unroll
      for (int j = 0; j < 4; ++j) bb_[j] = Ws[kk][tx * 4 + j];
#pragma unroll
      for (int i = 0; i < 4; ++i)
#pragma unroll
        for (int j = 0; j < 4; ++j) acc[i][j] += a[i] * bb_[j];
    }
    __syncthreads();
  }
#pragma unroll
  for (int i = 0; i < 4; ++i) {
    int m = m0 + ty * 4 + i;
#pragma unroll
    for (int j = 0; j < 4; ++j) {
      int n = n0 + tx * 4 + j;
      if (n >= N) continue;
      float v = acc[i][j];
      if (EPI >= 1) v += bias[n];
      if (EPI == 1) v = 0.5f * v * (1.f + erff(v * 0.70710678118f));
      C[(size_t)m * N + n] = v;
    }
  }
}

// ---------------- K4: dt = softplus(zx[...,896+h] + dt_bias[h])
__global__ void k_dt(const float* __restrict__ zx, const float* __restrict__ dt_bias,
                     float* __restrict__ dtb, int total) {
  int idx = blockIdx.x * 256 + threadIdx.x;  // g*L*6
  if (idx >= total) return;
  int h = idx % NHEAD; int bl = idx / NHEAD;
  float v = zx[(size_t)bl * DIP + 896 + h] + dt_bias[h];
  dtb[idx] = (v > 20.f) ? v : log1pf(expf(v));
}

// ---------------- K5: causal depthwise conv(4) + bias + silu -> xbc (g,L,512)
__global__ void k_conv(const float* __restrict__ zx, const float* __restrict__ cw,
                       const float* __restrict__ cb, float* __restrict__ xbc, int total) {
  int idx = blockIdx.x * 256 + threadIdx.x;  // g*L*512
  if (idx >= total) return;
  int ch = idx & 511; int l = (idx >> 9) & (LEN - 1); int bb = idx >> 21;
  float acc = cb[ch];
#pragma unroll
  for (int k = 0; k < 4; ++k) {
    int ll = l - 3 + k;
    if (ll >= 0) acc += zx[((size_t)bb * LEN + ll) * DIP + 384 + ch] * cw[ch * 4 + k];
  }
  xbc[idx] = acc / (1.f + expf(-acc));
}

// ---------------- K6: per (b,chunk,h): Y_diag -> y, chunk states -> states, Atot
__global__ __launch_bounds__(256) void k_ssd1(const float* __restrict__ xbc,
    const float* __restrict__ dtb, const float* __restrict__ A_log,
    float* __restrict__ y, float* __restrict__ states, float* __restrict__ Atot) {
  int cch = blockIdx.x, h = blockIdx.y, bb = blockIdx.z;
  int t = threadIdx.x;
  __shared__ float sA[256];
  __shared__ float Bm[256 * 65];
  __shared__ float Xs[256 * 65];
  size_t rowbase = (size_t)bb * LEN + cch * 256;
  float Ah = -expf(A_log[h]);
  float a = dtb[(rowbase + t) * NHEAD + h] * Ah;
  sA[t] = a;
  __syncthreads();
  for (int off = 1; off < 256; off <<= 1) {
    float v = (t >= off) ? sA[t - off] : 0.f;
    __syncthreads();
    sA[t] += v;
    __syncthreads();
  }
  float Acs_t = sA[t];
  float Atot_v = sA[255];
  // stage Cm via Xs, pull into regs
  for (int i = 0; i < 64; ++i) {
    int idx = t + i * 256;
    int s = idx >> 6, n = idx & 63;
    Xs[s * 65 + n] = xbc[(rowbase + s) * 512 + 448 + n];
  }
  __syncthreads();
  float cm[64];
#pragma unroll
  for (int n = 0; n < 64; ++n) cm[n] = Xs[t * 65 + n];
  __syncthreads();
  // stage Bm and x_in = xs*dt
  for (int i = 0; i < 64; ++i) {
    int idx = t + i * 256;
    int s = idx >> 6, n = idx & 63;
    Bm[s * 65 + n] = xbc[(rowbase + s) * 512 + 384 + n];
    Xs[s * 65 + n] = xbc[(rowbase + s) * 512 + h * 64 + n] * dtb[(rowbase + s) * NHEAD + h];
  }
  __syncthreads();
  // chunk states: states[p,n] = sum_t Bm[t,n]*exp(Atot - Acs[t])*x_in[t,p]
  {
    float stacc[16];
#pragma unroll
    for (int i = 0; i < 16; ++i) stacc[i] = 0.f;
    int p = t >> 2, n0 = (t & 3) * 16;
    for (int s = 0; s < 256; ++s) {
      float d = expf(Atot_v - sA[s]) * Xs[s * 65 + p];
#pragma unroll
      for (int i = 0; i < 16; ++i) stacc[i] += d * Bm[s * 65 + n0 + i];
    }
    size_t stbase = ((((size_t)bb * NCHK + cch) * NHEAD + h) * 64 + p) * 64 + n0;
#pragma unroll
    for (int i = 0; i < 16; ++i) states[stbase + i] = stacc[i];
    if (t == 0) Atot[((size_t)bb * NCHK + cch) * NHEAD + h] = Atot_v;
  }
  // Y_diag
  float yacc[64];
#pragma unroll
  for (int p = 0; p < 64; ++p) yacc[p] = 0.f;
  for (int s = 0; s <= t; ++s) {
    float dot = 0.f;
#pragma unroll
    for (int n = 0; n < 64; ++n) dot += cm[n] * Bm[s * 65 + n];
    float wgt = expf(Acs_t - sA[s]) * dot;
#pragma unroll
    for (int p = 0; p < 64; ++p) yacc[p] += wgt * Xs[s * 65 + p];
  }
  __syncthreads();
#pragma unroll
  for (int p = 0; p < 64; ++p) Bm[t * 65 + p] = yacc[p];
  __syncthreads();
  for (int i = 0; i < 64; ++i) {
    int idx = t + i * 256;
    int s = idx >> 6, pp = idx & 63;
    y[(rowbase + s) * DI + h * 64 + pp] = Bm[s * 65 + pp];
  }
}

// ---------------- K7: inter-chunk scan (sequential over 16 chunks)
__global__ void k_scan(const float* __restrict__ states, const float* __restrict__ Atot,
                       float* __restrict__ Sin) {
  int h = blockIdx.x, bb = blockIdx.y;
  int t = threadIdx.x;
  float S[16];
#pragma unroll
  for (int i = 0; i < 16; ++i) S[i] = 0.f;
  for (int z = 0; z < NCHK; ++z) {
    size_t base = (((size_t)bb * NCHK + z) * NHEAD + h) * 4096 + t * 16;
#pragma unroll
    for (int i = 0; i < 16; ++i) Sin[base + i] = S[i];
    float az = expf(Atot[((size_t)bb * NCHK + z) * NHEAD + h]);
#pragma unroll
    for (int i = 0; i < 16; ++i) S[i] = S[i] * az + states[base + i];
  }
}

// ---------------- K8: y += Y_off + xs*D_skip
__global__ __launch_bounds__(256) void k_ssd2(const float* __restrict__ xbc,
    const float* __restrict__ dtb, const float* __restrict__ A_log,
    const float* __restrict__ Dskip, const float* __restrict__ Sin, float* __restrict__ y) {
  int cch = blockIdx.x, h = blockIdx.y, bb = blockIdx.z;
  int t = threadIdx.x;
  __shared__ float sA[256];
  __shared__ float Sl[4096];
  __shared__ float Buf[256 * 65];
  size_t rowbase = (size_t)bb * LEN + cch * 256;
  float Ah = -expf(A_log[h]);
  sA[t] = dtb[(rowbase + t) * NHEAD + h] * Ah;
  __syncthreads();
  for (int off = 1; off < 256; off <<= 1) {
    float v = (t >= off) ? sA[t - off] : 0.f;
    __syncthreads();
    sA[t] += v;
    __syncthreads();
  }
  float et = expf(sA[t]);
  // stage Sin
  size_t sinbase = (((size_t)bb * NCHK + cch) * NHEAD + h) * 4096;
  for (int i = 0; i < 16; ++i) { int idx = t + i * 256; Sl[idx] = Sin[sinbase + idx]; }
  // stage Cm via Buf, pull to regs
  for (int i = 0; i < 64; ++i) {
    int idx = t + i * 256;
    int s = idx >> 6, n = idx & 63;
    Buf[s * 65 + n] = xbc[(rowbase + s) * 512 + 448 + n];
  }
  __syncthreads();
  float cm[64];
#pragma unroll
  for (int n = 0; n < 64; ++n) cm[n] = Buf[t * 65 + n];
  __syncthreads();
  // stage xs (raw, for D_skip)
  for (int i = 0; i < 64; ++i) {
    int idx = t + i * 256;
    int s = idx >> 6, n = idx & 63;
    Buf[s * 65 + n] = xbc[(rowbase + s) * 512 + h * 64 + n];
  }
  __syncthreads();
  float Dh = Dskip[h];
  float r[64];
#pragma unroll
  for (int p = 0; p < 64; ++p) {
    float acc = 0.f;
#pragma unroll
    for (int n = 0; n < 64; ++n) acc += cm[n] * Sl[p * 64 + n];
    r[p] = et * acc + Dh * Buf[t * 65 + p];
  }
  __syncthreads();
#pragma unroll
  for (int p = 0; p < 64; ++p) Buf[t * 65 + p] = r[p];
  __syncthreads();
  for (int i = 0; i < 64; ++i) {
    int idx = t + i * 256;
    int s = idx >> 6, pp = idx & 63;
    size_t o = (rowbase + s) * DI + h * 64 + pp;
    y[o] += Buf[s * 65 + pp];
  }
}

// ---------------- K9: g = y*silu(z); RMSNorm(384) * ssm_norm_w -> gn
__global__ __launch_bounds__(128) void k_gate(const float* __restrict__ y,
    const float* __restrict__ zx, const float* __restrict__ nw, float* __restrict__ gn) {
  int row = blockIdx.x;  // bb*LEN + l
  int tid = threadIdx.x;
  float g[3]; float sq = 0.f;
#pragma unroll
  for (int i = 0; i < 3; ++i) {
    int d = tid + i * 128;
    float z = zx[(size_t)row * DIP + d];
    float gg = y[(size_t)row * DI + d] * (z / (1.f + expf(-z)));
    g[i] = gg; sq += gg * gg;
  }
  for (int off = 32; off > 0; off >>= 1) sq += __shfl_down(sq, off);
  __shared__ float wsum[2];
  if ((tid & 63) == 0) wsum[tid >> 6] = sq;
  __syncthreads();
  float rs = rsqrtf((wsum[0] + wsum[1]) / 384.f + 1e-5f);
#pragma unroll
  for (int i = 0; i < 3; ++i) {
    int d = tid + i * 128;
    gn[(size_t)row * DI + d] = g[i] * rs * nw[d];
  }
}

// ---------------- K11: resid[b,t,c] = x[b,c,t] + m[b,t,c]
__global__ void k_resid(const float* __restrict__ x, const float* __restrict__ m,
                        float* __restrict__ r) {
  __shared__ float s[32][33];
  int bb = blockIdx.z; int c0 = blockIdx.y * 32; int t0 = blockIdx.x * 32;
  int tx = threadIdx.x, ty = threadIdx.y;
  for (int i = 0; i < 4; ++i)
    s[ty + i * 8][tx] = x[((size_t)bb * CHN + c0 + ty + i * 8) * LEN + t0 + tx];
  __syncthreads();
  for (int i = 0; i < 4; ++i) {
    size_t o = ((size_t)bb * LEN + t0 + ty + i * 8) * CHN + c0 + tx;
    r[o] = s[tx][ty + i * 8] + m[o];
  }
}

// ---------------- K12: plain LayerNorm over 192 (rowwise)
__global__ __launch_bounds__(64) void k_ln2(const float* __restrict__ r,
    const float* __restrict__ w, const float* __restrict__ b, float* __restrict__ h2) {
  int row = blockIdx.x;
  int tid = threadIdx.x;
  float v[3]; float sum = 0.f;
#pragma unroll
  for (int i = 0; i < 3; ++i) { v[i] = r[(size_t)row * CHN + tid + i * 64]; sum += v[i]; }
  for (int off = 32; off > 0; off >>= 1) sum += __shfl_down(sum, off);
  sum = __shfl(sum, 0);
  float mu = sum / 192.f;
  float sq = 0.f;
#pragma unroll
  for (int i = 0; i < 3; ++i) { float d = v[i] - mu; sq += d * d; }
  for (int off = 32; off > 0; off >>= 1) sq += __shfl_down(sq, off);
  sq = __shfl(sq, 0);
  float rs = rsqrtf(sq / 192.f + 1e-5f);
#pragma unroll
  for (int i = 0; i < 3; ++i) {
    int c = tid + i * 64;
    h2[(size_t)row * CHN + c] = (v[i] - mu) * rs * w[c] + b[c];
  }
}

// ---------------- K15: out[b,c,t] = resid[b,t,c] + f2[b,t,c]  (f32 out)
__global__ void k_out(const float* __restrict__ r, const float* __restrict__ f,
                      float* __restrict__ out) {
  __shared__ float s[32][33];
  int bb = blockIdx.z; int c0 = blockIdx.y * 32; int t0 = blockIdx.x * 32;
  int tx = threadIdx.x, ty = threadIdx.y;
  for (int i = 0; i < 4; ++i) {
    size_t o = ((size_t)bb * LEN + t0 + ty + i * 8) * CHN + c0 + tx;
    s[tx][ty + i * 8] = r[o] + f[o];
  }
  __syncthreads();
  for (int i = 0; i < 4; ++i)
    out[((size_t)bb * CHN + c0 + ty + i * 8) * LEN + t0 + tx] = s[ty + i * 8][tx];
}

extern "C" void kernel_launch(void* const* d_in, const int* in_sizes, int n_in,
                              void* d_out, int out_size, void* d_ws, size_t ws_size,
                              hipStream_t stream) {
  const float* x     = (const float*)d_in[0];
  const float* n1w   = (const float*)d_in[1];
  const float* n1b   = (const float*)d_in[2];
  const float* win   = (const float*)d_in[3];
  const float* cw    = (const float*)d_in[4];
  const float* cb    = (const float*)d_in[5];
  const float* dtbw  = (const float*)d_in[6];
  const float* alog  = (const float*)d_in[7];
  const float* dskip = (const float*)d_in[8];
  const float* snw   = (const float*)d_in[9];
  const float* wout  = (const float*)d_in[10];
  const float* n2w   = (const float*)d_in[11];
  const float* n2b   = (const float*)d_in[12];
  const float* w1    = (const float*)d_in[13];
  const float* b1    = (const float*)d_in[14];
  const float* w2    = (const float*)d_in[15];
  const float* b2    = (const float*)d_in[16];
  float* out = (float*)d_out;

  // adaptive group size: process g batches per pass so scratch fits ws_size
  int g = 4;
  for (;;) {
    size_t S_BLC = (size_t)g * LEN * CHN;
    size_t S_ZX  = (size_t)g * LEN * DIP;
    size_t S_DT  = (size_t)g * LEN * NHEAD;
    size_t S_XBC = (size_t)g * LEN * 512;
    size_t S_Y   = (size_t)g * LEN * DI;
    size_t S_ST  = (size_t)g * NCHK * NHEAD * 4096;
    size_t TOTAL = 2 * S_BLC + S_ZX + S_DT + S_XBC + S_Y + 2 * S_ST + 768;
    if (TOTAL * 4 <= ws_size) break;
    if (g == 1) return;  // cannot fit even one batch
    g >>= 1;
  }

  const size_t S_BLC = (size_t)g * LEN * CHN;
  const size_t S_ZX  = (size_t)g * LEN * DIP;
  const size_t S_DT  = (size_t)g * LEN * NHEAD;
  const size_t S_XBC = (size_t)g * LEN * 512;
  const size_t S_Y   = (size_t)g * LEN * DI;
  const size_t S_ST  = (size_t)g * NCHK * NHEAD * 4096;

  float* ws   = (float*)d_ws;
  float* h1   = ws;
  float* U    = ws + S_BLC;
  float* gn   = ws;                          // reuse h1+U after GEMM1 (2*S_BLC == S_Y)
  float* zx   = ws + 2 * S_BLC;
  float* h2   = zx;                          // reuse zx after gate
  float* f1   = zx + S_BLC;
  float* f2   = zx + S_BLC + S_Y;
  float* dtb  = zx + S_ZX;
  float* xbc  = dtb + S_DT;
  float* m_   = xbc;                         // reuse xbc after ssd2
  float* resid= xbc + S_BLC;
  float* yb   = xbc + S_XBC;
  float* st   = yb + S_Y;
  float* si   = st + S_ST;
  float* at   = si + S_ST;

  const int M = g * LEN;  // token rows per pass

  for (int b0 = 0; b0 < BATCH; b0 += g) {
    const float* xg  = x   + (size_t)b0 * CHN * LEN;
    float*       og  = out + (size_t)b0 * CHN * LEN;

    // 1. LN1 (transposing)
    k_ln1<<<dim3(LEN / 32, g), 256, 0, stream>>>(xg, n1w, n1b, h1);
    // 2. build u
    k_make_u<<<dim3(LEN / 32, CHN / 32, g), dim3(32, 8), 0, stream>>>(h1, U);
    // 3. in_proj GEMM: (M x 192)@(192 x 902)
    gemm_aw<0><<<dim3((DIP + 63) / 64, M / 64), 256, 0, stream>>>(
        U, win, nullptr, zx, M, DIP, CHN);
    // 4. dt
    k_dt<<<dim3((M * NHEAD + 255) / 256), 256, 0, stream>>>(zx, dtbw, dtb, M * NHEAD);
    // 5. conv + silu
    k_conv<<<dim3((M * 512 + 255) / 256), 256, 0, stream>>>(zx, cw, cb, xbc, M * 512);
    // 6. SSD intra-chunk
    k_ssd1<<<dim3(NCHK, NHEAD, g), 256, 0, stream>>>(xbc, dtb, alog, yb, st, at);
    // 7. inter-chunk scan
    k_scan<<<dim3(NHEAD, g), 256, 0, stream>>>(st, at, si);
    // 8. SSD off-diagonal + skip
    k_ssd2<<<dim3(NCHK, NHEAD, g), 256, 0, stream>>>(xbc, dtb, alog, dskip, si, yb);
    // 9. gate + RMSNorm
    k_gate<<<dim3(M), 128, 0, stream>>>(yb, zx, snw, gn);
    // 10. out_proj GEMM: (M x 384)@(384 x 192)
    gemm_aw<0><<<dim3(CHN / 64, M / 64), 256, 0, stream>>>(
        gn, wout, nullptr, m_, M, CHN, DI);
    // 11. residual 1 (transposed x add)
    k_resid<<<dim3(LEN / 32, CHN / 32, g), dim3(32, 8), 0, stream>>>(xg, m_, resid);
    // 12. LN2
    k_ln2<<<dim3(M), 64, 0, stream>>>(resid, n2w, n2b, h2);
    // 13. FFN1 + gelu
    gemm_aw<1><<<dim3(DI / 64, M / 64), 256, 0, stream>>>(
        h2, w1, b1, f1, M, DI, CHN);
    // 14. FFN2 + bias
    gemm_aw<2><<<dim3(CHN / 64, M / 64), 256, 0, stream>>>(
        f1, w2, b2, f2, M, CHN, DI);
    // 15. final residual + transpose to (B,C,H,W) f32
    k_out<<<dim3(LEN / 32, CHN / 32, g), dim3(32, 8), 0, stream>>>(resid, f2, og);
  }
}

// Round 5
// 1282.245 us; speedup vs baseline: 2.5702x; 2.5702x over previous
//
#include <hip/hip_runtime.h>
#include <hip/hip_bf16.h>

#define BATCH 8
#define CHN   192      // d_model
#define LEN   4096     // H*W tokens
#define DIP   902      // in_proj out dim
#define DI    384      // d_inner
#define NHEAD 6
#define HDIM  64
#define DST   64       // d_state
#define NCHK  16       // chunks (LEN/256)

// ---------------- K1: transposing LayerNorm1: x (g,192,L) f32 -> h1 (g,L,192) f32
__global__ __launch_bounds__(256) void k_ln1(const float* __restrict__ x,
    const float* __restrict__ w, const float* __restrict__ b, float* __restrict__ h1) {
  __shared__ float s[192][33];
  __shared__ float red[2][32][8];
  __shared__ float mu_s[32], rs_s[32];
  int bb = blockIdx.y;
  int t0 = blockIdx.x * 32;
  int tid = threadIdx.x;
  for (int i = 0; i < 24; ++i) {
    int idx = tid + i * 256;            // 192*32 = 6144
    int c = idx >> 5, tt = idx & 31;
    s[c][tt] = x[((size_t)bb * CHN + c) * LEN + t0 + tt];
  }
  __syncthreads();
  int tok = tid & 31, part = tid >> 5;
  float sum = 0.f, sq = 0.f;
  for (int c = part * 24; c < part * 24 + 24; ++c) { float v = s[c][tok]; sum += v; sq += v * v; }
  red[0][tok][part] = sum; red[1][tok][part] = sq;
  __syncthreads();
  if (tid < 32) {
    float su = 0.f, qq = 0.f;
    for (int p = 0; p < 8; ++p) { su += red[0][tid][p]; qq += red[1][tid][p]; }
    float mu = su / 192.f;
    float var = qq / 192.f - mu * mu;
    mu_s[tid] = mu; rs_s[tid] = rsqrtf(var + 1e-5f);
  }
  __syncthreads();
  for (int i = 0; i < 24; ++i) {
    int idx = tid + i * 256;
    int c = idx % 192, tt = idx / 192;
    float v = (s[c][tt] - mu_s[tt]) * rs_s[tt] * w[c] + b[c];
    h1[((size_t)bb * LEN + t0 + tt) * CHN + c] = v;
  }
}

// ---------------- K2: u[b,l,c2] = h1_flat[b][c2*LEN + l]  (flat reinterpretation transpose)
__global__ void k_make_u(const float* __restrict__ h1, float* __restrict__ U) {
  __shared__ float s[32][33];
  int bb = blockIdx.z;
  int c0 = blockIdx.y * 32;
  int l0 = blockIdx.x * 32;
  int tx = threadIdx.x, ty = threadIdx.y;
  const float* src = h1 + (size_t)bb * (CHN * LEN);
  for (int i = 0; i < 4; ++i)
    s[ty + i * 8][tx] = src[(size_t)(c0 + ty + i * 8) * LEN + l0 + tx];
  __syncthreads();
  float* dst = U + (size_t)bb * (CHN * LEN);
  for (int i = 0; i < 4; ++i)
    dst[(size_t)(l0 + ty + i * 8) * CHN + c0 + tx] = s[tx][ty + i * 8];
}

// ---------------- generic tiled GEMM: C[M,N] = A[M,K](f32) @ W[N,K]^T(f32), epilogues
// EPI 0: none ; 1: +bias then exact gelu ; 2: +bias
template <int EPI>
__global__ __launch_bounds__(256) void gemm_aw(const float* __restrict__ A,
    const float* __restrict__ W, const float* __restrict__ bias,
    float* __restrict__ C, int M, int N, int K) {
  __shared__ float As[32][65];
  __shared__ float Ws[32][65];
  int m0 = blockIdx.y * 64, n0 = blockIdx.x * 64;
  int tid = threadIdx.x;
  int tx = tid & 15, ty = tid >> 4;
  float acc[4][4] = {};
  for (int k0 = 0; k0 < K; k0 += 32) {
    for (int i = 0; i < 8; ++i) {
      int idx = tid + i * 256;
      int r = idx >> 5, c = idx & 31;
      As[c][r] = A[(size_t)(m0 + r) * K + k0 + c];
    }
    for (int i = 0; i < 8; ++i) {
      int idx = tid + i * 256;
      int r = idx >> 5, c = idx & 31;
      int n = n0 + r;
      Ws[c][r] = (n < N) ? W[(size_t)n * K + k0 + c] : 0.f;
    }
    __syncthreads();
#pragma unroll
    for (int kk = 0; kk < 32; ++kk) {
      float a[4], bb_[4];
#pragma unroll
      for (int i = 0; i < 4; ++i) a[i] = As[kk][ty * 4 + i];
#pragma unroll
      for (int j = 0; j < 4; ++j) bb_[j] = Ws[kk][tx * 4 + j];
#pragma unroll
      for (int i = 0; i < 4; ++i)
#pragma unroll
        for (int j = 0; j < 4; ++j) acc[i][j] += a[i] * bb_[j];
    }
    __syncthreads();
  }
#pragma unroll
  for (int i = 0; i < 4; ++i) {
    int m = m0 + ty * 4 + i;
#pragma unroll
    for (int j = 0; j < 4; ++j) {
      int n = n0 + tx * 4 + j;
      if (n >= N) continue;
      float v = acc[i][j];
      if (EPI >= 1) v += bias[n];
      if (EPI == 1) v = 0.5f * v * (1.f + erff(v * 0.70710678118f));
      C[(size_t)m * N + n] = v;
    }
  }
}

// ---------------- K4: dt = softplus(zx[...,896+h] + dt_bias[h])
__global__ void k_dt(const float* __restrict__ zx, const float* __restrict__ dt_bias,
                     float* __restrict__ dtb, int total) {
  int idx = blockIdx.x * 256 + threadIdx.x;  // g*L*6
  if (idx >= total) return;
  int h = idx % NHEAD; int bl = idx / NHEAD;
  float v = zx[(size_t)bl * DIP + 896 + h] + dt_bias[h];
  dtb[idx] = (v > 20.f) ? v : log1pf(expf(v));
}

// ---------------- K5: causal depthwise conv(4) + bias + silu -> xbc (g,L,512)
__global__ void k_conv(const float* __restrict__ zx, const float* __restrict__ cw,
                       const float* __restrict__ cb, float* __restrict__ xbc, int total) {
  int idx = blockIdx.x * 256 + threadIdx.x;  // g*L*512
  if (idx >= total) return;
  int ch = idx & 511; int l = (idx >> 9) & (LEN - 1); int bb = idx >> 21;
  float acc = cb[ch];
#pragma unroll
  for (int k = 0; k < 4; ++k) {
    int ll = l - 3 + k;
    if (ll >= 0) acc += zx[((size_t)bb * LEN + ll) * DIP + 384 + ch] * cw[ch * 4 + k];
  }
  xbc[idx] = acc / (1.f + expf(-acc));
}

// ---------------- K6 (rewritten): per (b,chunk,h): Y_diag, chunk states, Atot
// Two-phase register-tiled matmul. 256 threads as 16x16 grid, 4x4 regs each.
// LDS layouts transposed so inner loops are conflict-free ds_read_b128.
__global__ __launch_bounds__(256) void k_ssd1(const float* __restrict__ xbc,
    const float* __restrict__ dtb, const float* __restrict__ A_log,
    float* __restrict__ y, float* __restrict__ states, float* __restrict__ Atot) {
  int cch = blockIdx.x, h = blockIdx.y, bb = blockIdx.z;
  int tid = threadIdx.x;
  int tx = tid & 15, ty = tid >> 4;
  __shared__ float sA[256];
  __shared__ float sE[256];
  __shared__ float CpT[64][68];   // [n][t]  C-panel transposed
  __shared__ float BtT[64][68];   // [n][s]  B-tile transposed
  __shared__ float Xt [64][68];   // [s][p]  X-tile (dt-premultiplied)
  __shared__ float SpT[64][68];   // [s][t]  masked-scaled scores
  size_t rowbase = (size_t)bb * LEN + cch * 256;
  float Ah = -expf(A_log[h]);
  {
    float a = dtb[(rowbase + tid) * NHEAD + h] * Ah;
    sA[tid] = a;
    __syncthreads();
    for (int off = 1; off < 256; off <<= 1) {
      float v = (tid >= off) ? sA[tid - off] : 0.f;
      __syncthreads();
      sA[tid] += v;
      __syncthreads();
    }
  }
  float Atot_v = sA[255];
  sE[tid] = expf(Atot_v - sA[tid]);
  if (tid == 0) Atot[((size_t)bb * NCHK + cch) * NHEAD + h] = Atot_v;

  float sacc[4][4] = {};

  for (int tp = 0; tp < 4; ++tp) {
    __syncthreads();   // protect CpT restage vs prior phase-1 readers
    // stage CpT[n][t] = C[t][n]
#pragma unroll
    for (int i = 0; i < 4; ++i) {
      int idx = tid + i * 256;
      int r = idx >> 4, c4 = idx & 15;
      float4 v = *(const float4*)&xbc[(rowbase + tp * 64 + r) * 512 + 448 + c4 * 4];
      CpT[c4 * 4 + 0][r] = v.x;
      CpT[c4 * 4 + 1][r] = v.y;
      CpT[c4 * 4 + 2][r] = v.z;
      CpT[c4 * 4 + 3][r] = v.w;
    }
    float yacc[4][4] = {};
    for (int st = 0; st <= tp; ++st) {
      __syncthreads(); // protect BtT/Xt/SpT restage vs prior readers; CpT staged
#pragma unroll
      for (int i = 0; i < 4; ++i) {
        int idx = tid + i * 256;
        int r = idx >> 4, c4 = idx & 15;
        size_t grow = (size_t)(rowbase + st * 64 + r) * 512;
        float4 bv = *(const float4*)&xbc[grow + 384 + c4 * 4];
        BtT[c4 * 4 + 0][r] = bv.x;
        BtT[c4 * 4 + 1][r] = bv.y;
        BtT[c4 * 4 + 2][r] = bv.z;
        BtT[c4 * 4 + 3][r] = bv.w;
        float dtv = dtb[(rowbase + st * 64 + r) * NHEAD + h];
        float4 xv = *(const float4*)&xbc[grow + h * 64 + c4 * 4];
        xv.x *= dtv; xv.y *= dtv; xv.z *= dtv; xv.w *= dtv;
        *(float4*)&Xt[r][c4 * 4] = xv;
      }
      __syncthreads();
      // phase 1: p1[i][j] = dot(C[tb+i], B[sb+j]) over n=0..63
      float p1[4][4] = {};
#pragma unroll 8
      for (int n = 0; n < 64; ++n) {
        float4 cv = *(const float4*)&CpT[n][ty * 4];
        float4 bv = *(const float4*)&BtT[n][tx * 4];
        float ci[4] = {cv.x, cv.y, cv.z, cv.w};
        float bj[4] = {bv.x, bv.y, bv.z, bv.w};
#pragma unroll
        for (int i = 0; i < 4; ++i)
#pragma unroll
          for (int j = 0; j < 4; ++j) p1[i][j] += ci[i] * bj[j];
      }
      // scale + causal mask, write SpT[s][t]
      {
        int tb = tp * 64 + ty * 4;
        int sb = st * 64 + tx * 4;
        float At[4];
#pragma unroll
        for (int i = 0; i < 4; ++i) At[i] = sA[tb + i];
#pragma unroll
        for (int j = 0; j < 4; ++j) {
          int sg = sb + j;
          float As = sA[sg];
          float4 o;
          o.x = (sg <= tb + 0) ? expf(At[0] - As) * p1[0][j] : 0.f;
          o.y = (sg <= tb + 1) ? expf(At[1] - As) * p1[1][j] : 0.f;
          o.z = (sg <= tb + 2) ? expf(At[2] - As) * p1[2][j] : 0.f;
          o.w = (sg <= tb + 3) ? expf(At[3] - As) * p1[3][j] : 0.f;
          *(float4*)&SpT[tx * 4 + j][ty * 4] = o;
        }
      }
      // chunk-states accumulation: only during tp==3 (covers every s-tile once)
      if (tp == 3) {
#pragma unroll 4
        for (int s = 0; s < 64; s += 4) {
          float4 b0 = *(const float4*)&BtT[tx * 4 + 0][s];
          float4 b1 = *(const float4*)&BtT[tx * 4 + 1][s];
          float4 b2 = *(const float4*)&BtT[tx * 4 + 2][s];
          float4 b3 = *(const float4*)&BtT[tx * 4 + 3][s];
          float bw[4][4] = {{b0.x, b0.y, b0.z, b0.w},
                            {b1.x, b1.y, b1.z, b1.w},
                            {b2.x, b2.y, b2.z, b2.w},
                            {b3.x, b3.y, b3.z, b3.w}};  // [j][ss]
          float xw[4][4];                               // [ss][i]
#pragma unroll
          for (int ss = 0; ss < 4; ++ss) {
            float e = sE[st * 64 + s + ss];
            float4 xv = *(const float4*)&Xt[s + ss][ty * 4];
            xw[ss][0] = xv.x * e; xw[ss][1] = xv.y * e;
            xw[ss][2] = xv.z * e; xw[ss][3] = xv.w * e;
          }
#pragma unroll
          for (int i = 0; i < 4; ++i)
#pragma unroll
            for (int j = 0; j < 4; ++j)
              sacc[i][j] += xw[0][i] * bw[j][0] + xw[1][i] * bw[j][1]
                          + xw[2][i] * bw[j][2] + xw[3][i] * bw[j][3];
        }
      }
      __syncthreads();  // SpT visible
      // phase 2: yacc[i][j] += sum_s SpT[s][tb+i] * Xt[s][p=tx*4+j]
#pragma unroll 8
      for (int s = 0; s < 64; ++s) {
        float4 sv = *(const float4*)&SpT[s][ty * 4];
        float4 xv = *(const float4*)&Xt[s][tx * 4];
        float si_[4] = {sv.x, sv.y, sv.z, sv.w};
        float xj[4] = {xv.x, xv.y, xv.z, xv.w};
#pragma unroll
        for (int i = 0; i < 4; ++i)
#pragma unroll
          for (int j = 0; j < 4; ++j) yacc[i][j] += si_[i] * xj[j];
      }
    }
    // write Y_diag panel
#pragma unroll
    for (int i = 0; i < 4; ++i) {
      float4 o = {yacc[i][0], yacc[i][1], yacc[i][2], yacc[i][3]};
      *(float4*)&y[(rowbase + tp * 64 + ty * 4 + i) * DI + h * 64 + tx * 4] = o;
    }
  }
  // write chunk states: states[p][n]
  size_t stbase = (((size_t)bb * NCHK + cch) * NHEAD + h) * 4096;
#pragma unroll
  for (int i = 0; i < 4; ++i) {
    float4 o = {sacc[i][0], sacc[i][1], sacc[i][2], sacc[i][3]};
    *(float4*)&states[stbase + (ty * 4 + i) * 64 + tx * 4] = o;
  }
}

// ---------------- K7: inter-chunk scan (sequential over 16 chunks)
__global__ void k_scan(const float* __restrict__ states, const float* __restrict__ Atot,
                       float* __restrict__ Sin) {
  int h = blockIdx.x, bb = blockIdx.y;
  int t = threadIdx.x;
  float S[16];
#pragma unroll
  for (int i = 0; i < 16; ++i) S[i] = 0.f;
  for (int z = 0; z < NCHK; ++z) {
    size_t base = (((size_t)bb * NCHK + z) * NHEAD + h) * 4096 + t * 16;
#pragma unroll
    for (int i = 0; i < 16; ++i) Sin[base + i] = S[i];
    float az = expf(Atot[((size_t)bb * NCHK + z) * NHEAD + h]);
#pragma unroll
    for (int i = 0; i < 16; ++i) S[i] = S[i] * az + states[base + i];
  }
}

// ---------------- K8: y += Y_off + xs*D_skip
__global__ __launch_bounds__(256) void k_ssd2(const float* __restrict__ xbc,
    const float* __restrict__ dtb, const float* __restrict__ A_log,
    const float* __restrict__ Dskip, const float* __restrict__ Sin, float* __restrict__ y) {
  int cch = blockIdx.x, h = blockIdx.y, bb = blockIdx.z;
  int t = threadIdx.x;
  __shared__ float sA[256];
  __shared__ float Sl[4096];
  __shared__ float Buf[256 * 65];
  size_t rowbase = (size_t)bb * LEN + cch * 256;
  float Ah = -expf(A_log[h]);
  sA[t] = dtb[(rowbase + t) * NHEAD + h] * Ah;
  __syncthreads();
  for (int off = 1; off < 256; off <<= 1) {
    float v = (t >= off) ? sA[t - off] : 0.f;
    __syncthreads();
    sA[t] += v;
    __syncthreads();
  }
  float et = expf(sA[t]);
  // stage Sin
  size_t sinbase = (((size_t)bb * NCHK + cch) * NHEAD + h) * 4096;
  for (int i = 0; i < 16; ++i) { int idx = t + i * 256; Sl[idx] = Sin[sinbase + idx]; }
  // stage Cm via Buf, pull to regs
  for (int i = 0; i < 64; ++i) {
    int idx = t + i * 256;
    int s = idx >> 6, n = idx & 63;
    Buf[s * 65 + n] = xbc[(rowbase + s) * 512 + 448 + n];
  }
  __syncthreads();
  float cm[64];
#pragma unroll
  for (int n = 0; n < 64; ++n) cm[n] = Buf[t * 65 + n];
  __syncthreads();
  // stage xs (raw, for D_skip)
  for (int i = 0; i < 64; ++i) {
    int idx = t + i * 256;
    int s = idx >> 6, n = idx & 63;
    Buf[s * 65 + n] = xbc[(rowbase + s) * 512 + h * 64 + n];
  }
  __syncthreads();
  float Dh = Dskip[h];
  float r[64];
#pragma unroll
  for (int p = 0; p < 64; ++p) {
    float acc = 0.f;
#pragma unroll
    for (int n = 0; n < 64; ++n) acc += cm[n] * Sl[p * 64 + n];
    r[p] = et * acc + Dh * Buf[t * 65 + p];
  }
  __syncthreads();
#pragma unroll
  for (int p = 0; p < 64; ++p) Buf[t * 65 + p] = r[p];
  __syncthreads();
  for (int i = 0; i < 64; ++i) {
    int idx = t + i * 256;
    int s = idx >> 6, pp = idx & 63;
    size_t o = (rowbase + s) * DI + h * 64 + pp;
    y[o] += Buf[s * 65 + pp];
  }
}

// ---------------- K9: g = y*silu(z); RMSNorm(384) * ssm_norm_w -> gn
__global__ __launch_bounds__(128) void k_gate(const float* __restrict__ y,
    const float* __restrict__ zx, const float* __restrict__ nw, float* __restrict__ gn) {
  int row = blockIdx.x;  // bb*LEN + l
  int tid = threadIdx.x;
  float g[3]; float sq = 0.f;
#pragma unroll
  for (int i = 0; i < 3; ++i) {
    int d = tid + i * 128;
    float z = zx[(size_t)row * DIP + d];
    float gg = y[(size_t)row * DI + d] * (z / (1.f + expf(-z)));
    g[i] = gg; sq += gg * gg;
  }
  for (int off = 32; off > 0; off >>= 1) sq += __shfl_down(sq, off);
  __shared__ float wsum[2];
  if ((tid & 63) == 0) wsum[tid >> 6] = sq;
  __syncthreads();
  float rs = rsqrtf((wsum[0] + wsum[1]) / 384.f + 1e-5f);
#pragma unroll
  for (int i = 0; i < 3; ++i) {
    int d = tid + i * 128;
    gn[(size_t)row * DI + d] = g[i] * rs * nw[d];
  }
}

// ---------------- K11: resid[b,t,c] = x[b,c,t] + m[b,t,c]
__global__ void k_resid(const float* __restrict__ x, const float* __restrict__ m,
                        float* __restrict__ r) {
  __shared__ float s[32][33];
  int bb = blockIdx.z; int c0 = blockIdx.y * 32; int t0 = blockIdx.x * 32;
  int tx = threadIdx.x, ty = threadIdx.y;
  for (int i = 0; i < 4; ++i)
    s[ty + i * 8][tx] = x[((size_t)bb * CHN + c0 + ty + i * 8) * LEN + t0 + tx];
  __syncthreads();
  for (int i = 0; i < 4; ++i) {
    size_t o = ((size_t)bb * LEN + t0 + ty + i * 8) * CHN + c0 + tx;
    r[o] = s[tx][ty + i * 8] + m[o];
  }
}

// ---------------- K12: plain LayerNorm over 192 (rowwise)
__global__ __launch_bounds__(64) void k_ln2(const float* __restrict__ r,
    const float* __restrict__ w, const float* __restrict__ b, float* __restrict__ h2) {
  int row = blockIdx.x;
  int tid = threadIdx.x;
  float v[3]; float sum = 0.f;
#pragma unroll
  for (int i = 0; i < 3; ++i) { v[i] = r[(size_t)row * CHN + tid + i * 64]; sum += v[i]; }
  for (int off = 32; off > 0; off >>= 1) sum += __shfl_down(sum, off);
  sum = __shfl(sum, 0);
  float mu = sum / 192.f;
  float sq = 0.f;
#pragma unroll
  for (int i = 0; i < 3; ++i) { float d = v[i] - mu; sq += d * d; }
  for (int off = 32; off > 0; off >>= 1) sq += __shfl_down(sq, off);
  sq = __shfl(sq, 0);
  float rs = rsqrtf(sq / 192.f + 1e-5f);
#pragma unroll
  for (int i = 0; i < 3; ++i) {
    int c = tid + i * 64;
    h2[(size_t)row * CHN + c] = (v[i] - mu) * rs * w[c] + b[c];
  }
}

// ---------------- K15: out[b,c,t] = resid[b,t,c] + f2[b,t,c]  (f32 out)
__global__ void k_out(const float* __restrict__ r, const float* __restrict__ f,
                      float* __restrict__ out) {
  __shared__ float s[32][33];
  int bb = blockIdx.z; int c0 = blockIdx.y * 32; int t0 = blockIdx.x * 32;
  int tx = threadIdx.x, ty = threadIdx.y;
  for (int i = 0; i < 4; ++i) {
    size_t o = ((size_t)bb * LEN + t0 + ty + i * 8) * CHN + c0 + tx;
    s[tx][ty + i * 8] = r[o] + f[o];
  }
  __syncthreads();
  for (int i = 0; i < 4; ++i)
    out[((size_t)bb * CHN + c0 + ty + i * 8) * LEN + t0 + tx] = s[ty + i * 8][tx];
}

extern "C" void kernel_launch(void* const* d_in, const int* in_sizes, int n_in,
                              void* d_out, int out_size, void* d_ws, size_t ws_size,
                              hipStream_t stream) {
  const float* x     = (const float*)d_in[0];
  const float* n1w   = (const float*)d_in[1];
  const float* n1b   = (const float*)d_in[2];
  const float* win   = (const float*)d_in[3];
  const float* cw    = (const float*)d_in[4];
  const float* cb    = (const float*)d_in[5];
  const float* dtbw  = (const float*)d_in[6];
  const float* alog  = (const float*)d_in[7];
  const float* dskip = (const float*)d_in[8];
  const float* snw   = (const float*)d_in[9];
  const float* wout  = (const float*)d_in[10];
  const float* n2w   = (const float*)d_in[11];
  const float* n2b   = (const float*)d_in[12];
  const float* w1    = (const float*)d_in[13];
  const float* b1    = (const float*)d_in[14];
  const float* w2    = (const float*)d_in[15];
  const float* b2    = (const float*)d_in[16];
  float* out = (float*)d_out;

  // adaptive group size: process g batches per pass so scratch fits ws_size
  int g = 4;
  for (;;) {
    size_t S_BLC = (size_t)g * LEN * CHN;
    size_t S_ZX  = (size_t)g * LEN * DIP;
    size_t S_DT  = (size_t)g * LEN * NHEAD;
    size_t S_XBC = (size_t)g * LEN * 512;
    size_t S_Y   = (size_t)g * LEN * DI;
    size_t S_ST  = (size_t)g * NCHK * NHEAD * 4096;
    size_t TOTAL = 2 * S_BLC + S_ZX + S_DT + S_XBC + S_Y + 2 * S_ST + 768;
    if (TOTAL * 4 <= ws_size) break;
    if (g == 1) return;  // cannot fit even one batch
    g >>= 1;
  }

  const size_t S_BLC = (size_t)g * LEN * CHN;
  const size_t S_ZX  = (size_t)g * LEN * DIP;
  const size_t S_DT  = (size_t)g * LEN * NHEAD;
  const size_t S_XBC = (size_t)g * LEN * 512;
  const size_t S_Y   = (size_t)g * LEN * DI;
  const size_t S_ST  = (size_t)g * NCHK * NHEAD * 4096;

  float* ws   = (float*)d_ws;
  float* h1   = ws;
  float* U    = ws + S_BLC;
  float* gn   = ws;                          // reuse h1+U after GEMM1 (2*S_BLC == S_Y)
  float* zx   = ws + 2 * S_BLC;
  float* h2   = zx;                          // reuse zx after gate
  float* f1   = zx + S_BLC;
  float* f2   = zx + S_BLC + S_Y;
  float* dtb  = zx + S_ZX;
  float* xbc  = dtb + S_DT;
  float* m_   = xbc;                         // reuse xbc after ssd2
  float* resid= xbc + S_BLC;
  float* yb   = xbc + S_XBC;
  float* st   = yb + S_Y;
  float* si   = st + S_ST;
  float* at   = si + S_ST;

  const int M = g * LEN;  // token rows per pass

  for (int b0 = 0; b0 < BATCH; b0 += g) {
    const float* xg  = x   + (size_t)b0 * CHN * LEN;
    float*       og  = out + (size_t)b0 * CHN * LEN;

    // 1. LN1 (transposing)
    k_ln1<<<dim3(LEN / 32, g), 256, 0, stream>>>(xg, n1w, n1b, h1);
    // 2. build u
    k_make_u<<<dim3(LEN / 32, CHN / 32, g), dim3(32, 8), 0, stream>>>(h1, U);
    // 3. in_proj GEMM: (M x 192)@(192 x 902)
    gemm_aw<0><<<dim3((DIP + 63) / 64, M / 64), 256, 0, stream>>>(
        U, win, nullptr, zx, M, DIP, CHN);
    // 4. dt
    k_dt<<<dim3((M * NHEAD + 255) / 256), 256, 0, stream>>>(zx, dtbw, dtb, M * NHEAD);
    // 5. conv + silu
    k_conv<<<dim3((M * 512 + 255) / 256), 256, 0, stream>>>(zx, cw, cb, xbc, M * 512);
    // 6. SSD intra-chunk (register-tiled two-phase matmul)
    k_ssd1<<<dim3(NCHK, NHEAD, g), 256, 0, stream>>>(xbc, dtb, alog, yb, st, at);
    // 7. inter-chunk scan
    k_scan<<<dim3(NHEAD, g), 256, 0, stream>>>(st, at, si);
    // 8. SSD off-diagonal + skip
    k_ssd2<<<dim3(NCHK, NHEAD, g), 256, 0, stream>>>(xbc, dtb, alog, dskip, si, yb);
    // 9. gate + RMSNorm
    k_gate<<<dim3(M), 128, 0, stream>>>(yb, zx, snw, gn);
    // 10. out_proj GEMM: (M x 384)@(384 x 192)
    gemm_aw<0><<<dim3(CHN / 64, M / 64), 256, 0, stream>>>(
        gn, wout, nullptr, m_, M, CHN, DI);
    // 11. residual 1 (transposed x add)
    k_resid<<<dim3(LEN / 32, CHN / 32, g), dim3(32, 8), 0, stream>>>(xg, m_, resid);
    // 12. LN2
    k_ln2<<<dim3(M), 64, 0, stream>>>(resid, n2w, n2b, h2);
    // 13. FFN1 + gelu
    gemm_aw<1><<<dim3(DI / 64, M / 64), 256, 0, stream>>>(
        h2, w1, b1, f1, M, DI, CHN);
    // 14. FFN2 + bias
    gemm_aw<2><<<dim3(CHN / 64, M / 64), 256, 0, stream>>>(
        f1, w2, b2, f2, M, CHN, DI);
    // 15. final residual + transpose to (B,C,H,W) f32
    k_out<<<dim3(LEN / 32, CHN / 32, g), dim3(32, 8), 0, stream>>>(resid, f2, og);
  }
}

// Round 6
// 900.672 us; speedup vs baseline: 3.6590x; 1.4237x over previous
//
#include <hip/hip_runtime.h>
#include <hip/hip_bf16.h>

#define BATCH 8
#define CHN   192      // d_model
#define LEN   4096     // H*W tokens
#define DIP   902      // in_proj out dim
#define DI    384      // d_inner
#define NHEAD 6
#define HDIM  64
#define DST   64       // d_state
#define NCHK  16       // chunks (LEN/256)

typedef __attribute__((ext_vector_type(8))) short short8;
typedef __attribute__((ext_vector_type(4))) float f32x4;

__device__ __forceinline__ short f2b(float f) {
  unsigned u = __builtin_bit_cast(unsigned, f);
  unsigned r = (u + 0x7FFFu + ((u >> 16) & 1u)) >> 16;  // round-to-nearest-even
  return (short)r;
}

// ---------------- K1: transposing LayerNorm1: x (g,192,L) f32 -> h1 (g,L,192) f32
__global__ __launch_bounds__(256) void k_ln1(const float* __restrict__ x,
    const float* __restrict__ w, const float* __restrict__ b, float* __restrict__ h1) {
  __shared__ float s[192][33];
  __shared__ float red[2][32][8];
  __shared__ float mu_s[32], rs_s[32];
  int bb = blockIdx.y;
  int t0 = blockIdx.x * 32;
  int tid = threadIdx.x;
  for (int i = 0; i < 24; ++i) {
    int idx = tid + i * 256;            // 192*32 = 6144
    int c = idx >> 5, tt = idx & 31;
    s[c][tt] = x[((size_t)bb * CHN + c) * LEN + t0 + tt];
  }
  __syncthreads();
  int tok = tid & 31, part = tid >> 5;
  float sum = 0.f, sq = 0.f;
  for (int c = part * 24; c < part * 24 + 24; ++c) { float v = s[c][tok]; sum += v; sq += v * v; }
  red[0][tok][part] = sum; red[1][tok][part] = sq;
  __syncthreads();
  if (tid < 32) {
    float su = 0.f, qq = 0.f;
    for (int p = 0; p < 8; ++p) { su += red[0][tid][p]; qq += red[1][tid][p]; }
    float mu = su / 192.f;
    float var = qq / 192.f - mu * mu;
    mu_s[tid] = mu; rs_s[tid] = rsqrtf(var + 1e-5f);
  }
  __syncthreads();
  for (int i = 0; i < 24; ++i) {
    int idx = tid + i * 256;
    int c = idx % 192, tt = idx / 192;
    float v = (s[c][tt] - mu_s[tt]) * rs_s[tt] * w[c] + b[c];
    h1[((size_t)bb * LEN + t0 + tt) * CHN + c] = v;
  }
}

// ---------------- K2: u[b,l,c2] = h1_flat[b][c2*LEN + l]
__global__ void k_make_u(const float* __restrict__ h1, float* __restrict__ U) {
  __shared__ float s[32][33];
  int bb = blockIdx.z;
  int c0 = blockIdx.y * 32;
  int l0 = blockIdx.x * 32;
  int tx = threadIdx.x, ty = threadIdx.y;
  const float* src = h1 + (size_t)bb * (CHN * LEN);
  for (int i = 0; i < 4; ++i)
    s[ty + i * 8][tx] = src[(size_t)(c0 + ty + i * 8) * LEN + l0 + tx];
  __syncthreads();
  float* dst = U + (size_t)bb * (CHN * LEN);
  for (int i = 0; i < 4; ++i)
    dst[(size_t)(l0 + ty + i * 8) * CHN + c0 + tx] = s[tx][ty + i * 8];
}

// ---------------- MFMA GEMM: C[M,N](f32,ldc) = A[M,K](f32->bf16) @ W[N,K]^T(f32->bf16)
// BM=128, BN=64, BK=64. 4 waves, each 64(m)x32(n): 4x2 16x16 MFMA tiles.
// LDS XOR-swizzle (byte ^= (row&7)<<4) -> conflict-free ds_read_b128 frag loads.
// EPI 0: none ; 1: +bias then exact gelu ; 2: +bias
template <int EPI>
__global__ __launch_bounds__(256) void gemm_mfma(const float* __restrict__ A,
    const float* __restrict__ W, const float* __restrict__ bias,
    float* __restrict__ C, int M, int N, int K, int ldc) {
  __shared__ short Al[128 * 64];  // row stride 128 B
  __shared__ short Wl[64 * 64];
  int m0 = blockIdx.y * 128, n0 = blockIdx.x * 64;
  int tid = threadIdx.x;
  int lane = tid & 63, wv = tid >> 6;
  int wm = (wv >> 1) * 64, wn = (wv & 1) * 32;
  int l15 = lane & 15, l4 = lane >> 4;
  f32x4 acc[4][2] = {};

  // staging coords
  int ra = tid >> 1, ca = (tid & 1) * 32;          // A: 2 thr/row, 32 cols each
  int rw = tid >> 2, cw = (tid & 3) * 16;          // W: 4 thr/row, 16 cols each
  char* ArowL = (char*)Al + ra * 128;
  char* WrowL = (char*)Wl + rw * 128;
  int rxa = (ra & 7) << 4, rxw = (rw & 7) << 4;

  for (int k0 = 0; k0 < K; k0 += 64) {
    const float* Ag = A + (size_t)(m0 + ra) * K + k0 + ca;
    const float* Wg = W + (size_t)(n0 + rw) * K + k0 + cw;
#pragma unroll
    for (int q = 0; q < 4; ++q) {
      float4 v0 = *(const float4*)(Ag + q * 8);
      float4 v1 = *(const float4*)(Ag + q * 8 + 4);
      short8 pk;
      pk[0] = f2b(v0.x); pk[1] = f2b(v0.y); pk[2] = f2b(v0.z); pk[3] = f2b(v0.w);
      pk[4] = f2b(v1.x); pk[5] = f2b(v1.y); pk[6] = f2b(v1.z); pk[7] = f2b(v1.w);
      *(short8*)(ArowL + (((ca + q * 8) * 2) ^ rxa)) = pk;
    }
#pragma unroll
    for (int q = 0; q < 2; ++q) {
      float4 v0 = *(const float4*)(Wg + q * 8);
      float4 v1 = *(const float4*)(Wg + q * 8 + 4);
      short8 pk;
      pk[0] = f2b(v0.x); pk[1] = f2b(v0.y); pk[2] = f2b(v0.z); pk[3] = f2b(v0.w);
      pk[4] = f2b(v1.x); pk[5] = f2b(v1.y); pk[6] = f2b(v1.z); pk[7] = f2b(v1.w);
      *(short8*)(WrowL + (((cw + q * 8) * 2) ^ rxw)) = pk;
    }
    __syncthreads();
#pragma unroll
    for (int ks = 0; ks < 64; ks += 32) {
      short8 af[4], wf[2];
#pragma unroll
      for (int mf = 0; mf < 4; ++mf) {
        int rr = wm + mf * 16 + l15;
        af[mf] = *(const short8*)((const char*)Al + rr * 128 +
                                  (((ks + l4 * 8) * 2) ^ ((rr & 7) << 4)));
      }
#pragma unroll
      for (int nf = 0; nf < 2; ++nf) {
        int rr = wn + nf * 16 + l15;
        wf[nf] = *(const short8*)((const char*)Wl + rr * 128 +
                                  (((ks + l4 * 8) * 2) ^ ((rr & 7) << 4)));
      }
#pragma unroll
      for (int mf = 0; mf < 4; ++mf)
#pragma unroll
        for (int nf = 0; nf < 2; ++nf)
          acc[mf][nf] = __builtin_amdgcn_mfma_f32_16x16x32_bf16(
              af[mf], wf[nf], acc[mf][nf], 0, 0, 0);
    }
    __syncthreads();
  }
#pragma unroll
  for (int mf = 0; mf < 4; ++mf) {
#pragma unroll
    for (int nf = 0; nf < 2; ++nf) {
      int col = n0 + wn + nf * 16 + l15;
      float bv = (EPI >= 1) ? bias[col] : 0.f;
#pragma unroll
      for (int reg = 0; reg < 4; ++reg) {
        int row = m0 + wm + mf * 16 + l4 * 4 + reg;
        float v = acc[mf][nf][reg];
        if (EPI >= 1) v += bv;
        if (EPI == 1) v = 0.5f * v * (1.f + erff(v * 0.70710678118f));
        C[(size_t)row * ldc + col] = v;
      }
    }
  }
}

// ---------------- K4: dt computed EXACTLY in f32 from U (dt precision is exp-critical)
// dt[row,h] = softplus( dot(U[row,:], win[896+h,:]) + dt_bias[h] )
__global__ __launch_bounds__(256) void k_dt2(const float* __restrict__ U,
    const float* __restrict__ win, const float* __restrict__ dt_bias,
    float* __restrict__ dtb) {
  __shared__ float Wl[6][192];
  int tid = threadIdx.x;
  for (int i = tid; i < 6 * 192; i += 256)
    Wl[i / 192][i % 192] = win[(size_t)(896 + i / 192) * 192 + (i % 192)];
  __syncthreads();
  int lane = tid & 63, wv = tid >> 6;
  int row = blockIdx.x * 4 + wv;
  float u0 = U[(size_t)row * 192 + lane];
  float u1 = U[(size_t)row * 192 + lane + 64];
  float u2 = U[(size_t)row * 192 + lane + 128];
  float acc[6];
#pragma unroll
  for (int h = 0; h < 6; ++h) {
    float p = u0 * Wl[h][lane] + u1 * Wl[h][lane + 64] + u2 * Wl[h][lane + 128];
    for (int off = 32; off > 0; off >>= 1) p += __shfl_down(p, off);
    acc[h] = p;
  }
  if (lane == 0) {
#pragma unroll
    for (int h = 0; h < 6; ++h) {
      float v = acc[h] + dt_bias[h];
      dtb[(size_t)row * NHEAD + h] = (v > 20.f) ? v : log1pf(expf(v));
    }
  }
}

// ---------------- K5: causal depthwise conv(4) + bias + silu -> xbc (g,L,512)
__global__ void k_conv(const float* __restrict__ zx, const float* __restrict__ cw,
                       const float* __restrict__ cb, float* __restrict__ xbc, int total) {
  int idx = blockIdx.x * 256 + threadIdx.x;  // g*L*512
  if (idx >= total) return;
  int ch = idx & 511; int l = (idx >> 9) & (LEN - 1); int bb = idx >> 21;
  float acc = cb[ch];
#pragma unroll
  for (int k = 0; k < 4; ++k) {
    int ll = l - 3 + k;
    if (ll >= 0) acc += zx[((size_t)bb * LEN + ll) * DIP + 384 + ch] * cw[ch * 4 + k];
  }
  xbc[idx] = acc / (1.f + expf(-acc));
}

// ---------------- K6: per (b,chunk,h): Y_diag, chunk states, Atot (register-tiled)
__global__ __launch_bounds__(256) void k_ssd1(const float* __restrict__ xbc,
    const float* __restrict__ dtb, const float* __restrict__ A_log,
    float* __restrict__ y, float* __restrict__ states, float* __restrict__ Atot) {
  int cch = blockIdx.x, h = blockIdx.y, bb = blockIdx.z;
  int tid = threadIdx.x;
  int tx = tid & 15, ty = tid >> 4;
  __shared__ float sA[256];
  __shared__ float sE[256];
  __shared__ float CpT[64][68];   // [n][t]
  __shared__ float BtT[64][68];   // [n][s]
  __shared__ float Xt [64][68];   // [s][p]
  __shared__ float SpT[64][68];   // [s][t]
  size_t rowbase = (size_t)bb * LEN + cch * 256;
  float Ah = -expf(A_log[h]);
  {
    float a = dtb[(rowbase + tid) * NHEAD + h] * Ah;
    sA[tid] = a;
    __syncthreads();
    for (int off = 1; off < 256; off <<= 1) {
      float v = (tid >= off) ? sA[tid - off] : 0.f;
      __syncthreads();
      sA[tid] += v;
      __syncthreads();
    }
  }
  float Atot_v = sA[255];
  sE[tid] = expf(Atot_v - sA[tid]);
  if (tid == 0) Atot[((size_t)bb * NCHK + cch) * NHEAD + h] = Atot_v;

  float sacc[4][4] = {};

  for (int tp = 0; tp < 4; ++tp) {
    __syncthreads();
#pragma unroll
    for (int i = 0; i < 4; ++i) {
      int idx = tid + i * 256;
      int r = idx >> 4, c4 = idx & 15;
      float4 v = *(const float4*)&xbc[(rowbase + tp * 64 + r) * 512 + 448 + c4 * 4];
      CpT[c4 * 4 + 0][r] = v.x;
      CpT[c4 * 4 + 1][r] = v.y;
      CpT[c4 * 4 + 2][r] = v.z;
      CpT[c4 * 4 + 3][r] = v.w;
    }
    float yacc[4][4] = {};
    for (int st = 0; st <= tp; ++st) {
      __syncthreads();
#pragma unroll
      for (int i = 0; i < 4; ++i) {
        int idx = tid + i * 256;
        int r = idx >> 4, c4 = idx & 15;
        size_t grow = (size_t)(rowbase + st * 64 + r) * 512;
        float4 bv = *(const float4*)&xbc[grow + 384 + c4 * 4];
        BtT[c4 * 4 + 0][r] = bv.x;
        BtT[c4 * 4 + 1][r] = bv.y;
        BtT[c4 * 4 + 2][r] = bv.z;
        BtT[c4 * 4 + 3][r] = bv.w;
        float dtv = dtb[(rowbase + st * 64 + r) * NHEAD + h];
        float4 xv = *(const float4*)&xbc[grow + h * 64 + c4 * 4];
        xv.x *= dtv; xv.y *= dtv; xv.z *= dtv; xv.w *= dtv;
        *(float4*)&Xt[r][c4 * 4] = xv;
      }
      __syncthreads();
      float p1[4][4] = {};
#pragma unroll 8
      for (int n = 0; n < 64; ++n) {
        float4 cv = *(const float4*)&CpT[n][ty * 4];
        float4 bv = *(const float4*)&BtT[n][tx * 4];
        float ci[4] = {cv.x, cv.y, cv.z, cv.w};
        float bj[4] = {bv.x, bv.y, bv.z, bv.w};
#pragma unroll
        for (int i = 0; i < 4; ++i)
#pragma unroll
          for (int j = 0; j < 4; ++j) p1[i][j] += ci[i] * bj[j];
      }
      {
        int tb = tp * 64 + ty * 4;
        int sb = st * 64 + tx * 4;
        float At[4];
#pragma unroll
        for (int i = 0; i < 4; ++i) At[i] = sA[tb + i];
#pragma unroll
        for (int j = 0; j < 4; ++j) {
          int sg = sb + j;
          float As = sA[sg];
          float4 o;
          o.x = (sg <= tb + 0) ? expf(At[0] - As) * p1[0][j] : 0.f;
          o.y = (sg <= tb + 1) ? expf(At[1] - As) * p1[1][j] : 0.f;
          o.z = (sg <= tb + 2) ? expf(At[2] - As) * p1[2][j] : 0.f;
          o.w = (sg <= tb + 3) ? expf(At[3] - As) * p1[3][j] : 0.f;
          *(float4*)&SpT[tx * 4 + j][ty * 4] = o;
        }
      }
      if (tp == 3) {
#pragma unroll 4
        for (int s = 0; s < 64; s += 4) {
          float4 b0 = *(const float4*)&BtT[tx * 4 + 0][s];
          float4 b1 = *(const float4*)&BtT[tx * 4 + 1][s];
          float4 b2 = *(const float4*)&BtT[tx * 4 + 2][s];
          float4 b3 = *(const float4*)&BtT[tx * 4 + 3][s];
          float bw[4][4] = {{b0.x, b0.y, b0.z, b0.w},
                            {b1.x, b1.y, b1.z, b1.w},
                            {b2.x, b2.y, b2.z, b2.w},
                            {b3.x, b3.y, b3.z, b3.w}};
          float xw[4][4];
#pragma unroll
          for (int ss = 0; ss < 4; ++ss) {
            float e = sE[st * 64 + s + ss];
            float4 xv = *(const float4*)&Xt[s + ss][ty * 4];
            xw[ss][0] = xv.x * e; xw[ss][1] = xv.y * e;
            xw[ss][2] = xv.z * e; xw[ss][3] = xv.w * e;
          }
#pragma unroll
          for (int i = 0; i < 4; ++i)
#pragma unroll
            for (int j = 0; j < 4; ++j)
              sacc[i][j] += xw[0][i] * bw[j][0] + xw[1][i] * bw[j][1]
                          + xw[2][i] * bw[j][2] + xw[3][i] * bw[j][3];
        }
      }
      __syncthreads();
#pragma unroll 8
      for (int s = 0; s < 64; ++s) {
        float4 sv = *(const float4*)&SpT[s][ty * 4];
        float4 xv = *(const float4*)&Xt[s][tx * 4];
        float si_[4] = {sv.x, sv.y, sv.z, sv.w};
        float xj[4] = {xv.x, xv.y, xv.z, xv.w};
#pragma unroll
        for (int i = 0; i < 4; ++i)
#pragma unroll
          for (int j = 0; j < 4; ++j) yacc[i][j] += si_[i] * xj[j];
      }
    }
#pragma unroll
    for (int i = 0; i < 4; ++i) {
      float4 o = {yacc[i][0], yacc[i][1], yacc[i][2], yacc[i][3]};
      *(float4*)&y[(rowbase + tp * 64 + ty * 4 + i) * DI + h * 64 + tx * 4] = o;
    }
  }
  size_t stbase = (((size_t)bb * NCHK + cch) * NHEAD + h) * 4096;
#pragma unroll
  for (int i = 0; i < 4; ++i) {
    float4 o = {sacc[i][0], sacc[i][1], sacc[i][2], sacc[i][3]};
    *(float4*)&states[stbase + (ty * 4 + i) * 64 + tx * 4] = o;
  }
}

// ---------------- K7: inter-chunk scan (sequential over 16 chunks)
__global__ void k_scan(const float* __restrict__ states, const float* __restrict__ Atot,
                       float* __restrict__ Sin) {
  int h = blockIdx.x, bb = blockIdx.y;
  int t = threadIdx.x;
  float S[16];
#pragma unroll
  for (int i = 0; i < 16; ++i) S[i] = 0.f;
  for (int z = 0; z < NCHK; ++z) {
    size_t base = (((size_t)bb * NCHK + z) * NHEAD + h) * 4096 + t * 16;
#pragma unroll
    for (int i = 0; i < 16; ++i) Sin[base + i] = S[i];
    float az = expf(Atot[((size_t)bb * NCHK + z) * NHEAD + h]);
#pragma unroll
    for (int i = 0; i < 16; ++i) S[i] = S[i] * az + states[base + i];
  }
}

// ---------------- K8: y += Y_off + xs*D_skip
__global__ __launch_bounds__(256) void k_ssd2(const float* __restrict__ xbc,
    const float* __restrict__ dtb, const float* __restrict__ A_log,
    const float* __restrict__ Dskip, const float* __restrict__ Sin, float* __restrict__ y) {
  int cch = blockIdx.x, h = blockIdx.y, bb = blockIdx.z;
  int t = threadIdx.x;
  __shared__ float sA[256];
  __shared__ float Sl[4096];
  __shared__ float Buf[256 * 65];
  size_t rowbase = (size_t)bb * LEN + cch * 256;
  float Ah = -expf(A_log[h]);
  sA[t] = dtb[(rowbase + t) * NHEAD + h] * Ah;
  __syncthreads();
  for (int off = 1; off < 256; off <<= 1) {
    float v = (t >= off) ? sA[t - off] : 0.f;
    __syncthreads();
    sA[t] += v;
    __syncthreads();
  }
  float et = expf(sA[t]);
  size_t sinbase = (((size_t)bb * NCHK + cch) * NHEAD + h) * 4096;
  for (int i = 0; i < 16; ++i) { int idx = t + i * 256; Sl[idx] = Sin[sinbase + idx]; }
  for (int i = 0; i < 64; ++i) {
    int idx = t + i * 256;
    int s = idx >> 6, n = idx & 63;
    Buf[s * 65 + n] = xbc[(rowbase + s) * 512 + 448 + n];
  }
  __syncthreads();
  float cm[64];
#pragma unroll
  for (int n = 0; n < 64; ++n) cm[n] = Buf[t * 65 + n];
  __syncthreads();
  for (int i = 0; i < 64; ++i) {
    int idx = t + i * 256;
    int s = idx >> 6, n = idx & 63;
    Buf[s * 65 + n] = xbc[(rowbase + s) * 512 + h * 64 + n];
  }
  __syncthreads();
  float Dh = Dskip[h];
  float r[64];
#pragma unroll
  for (int p = 0; p < 64; ++p) {
    float acc = 0.f;
#pragma unroll
    for (int n = 0; n < 64; ++n) acc += cm[n] * Sl[p * 64 + n];
    r[p] = et * acc + Dh * Buf[t * 65 + p];
  }
  __syncthreads();
#pragma unroll
  for (int p = 0; p < 64; ++p) Buf[t * 65 + p] = r[p];
  __syncthreads();
  for (int i = 0; i < 64; ++i) {
    int idx = t + i * 256;
    int s = idx >> 6, pp = idx & 63;
    size_t o = (rowbase + s) * DI + h * 64 + pp;
    y[o] += Buf[s * 65 + pp];
  }
}

// ---------------- K9: g = y*silu(z); RMSNorm(384) * ssm_norm_w -> gn
__global__ __launch_bounds__(128) void k_gate(const float* __restrict__ y,
    const float* __restrict__ zx, const float* __restrict__ nw, float* __restrict__ gn) {
  int row = blockIdx.x;
  int tid = threadIdx.x;
  float g[3]; float sq = 0.f;
#pragma unroll
  for (int i = 0; i < 3; ++i) {
    int d = tid + i * 128;
    float z = zx[(size_t)row * DIP + d];
    float gg = y[(size_t)row * DI + d] * (z / (1.f + expf(-z)));
    g[i] = gg; sq += gg * gg;
  }
  for (int off = 32; off > 0; off >>= 1) sq += __shfl_down(sq, off);
  __shared__ float wsum[2];
  if ((tid & 63) == 0) wsum[tid >> 6] = sq;
  __syncthreads();
  float rs = rsqrtf((wsum[0] + wsum[1]) / 384.f + 1e-5f);
#pragma unroll
  for (int i = 0; i < 3; ++i) {
    int d = tid + i * 128;
    gn[(size_t)row * DI + d] = g[i] * rs * nw[d];
  }
}

// ---------------- K11: resid[b,t,c] = x[b,c,t] + m[b,t,c]
__global__ void k_resid(const float* __restrict__ x, const float* __restrict__ m,
                        float* __restrict__ r) {
  __shared__ float s[32][33];
  int bb = blockIdx.z; int c0 = blockIdx.y * 32; int t0 = blockIdx.x * 32;
  int tx = threadIdx.x, ty = threadIdx.y;
  for (int i = 0; i < 4; ++i)
    s[ty + i * 8][tx] = x[((size_t)bb * CHN + c0 + ty + i * 8) * LEN + t0 + tx];
  __syncthreads();
  for (int i = 0; i < 4; ++i) {
    size_t o = ((size_t)bb * LEN + t0 + ty + i * 8) * CHN + c0 + tx;
    r[o] = s[tx][ty + i * 8] + m[o];
  }
}

// ---------------- K12: plain LayerNorm over 192 (rowwise)
__global__ __launch_bounds__(64) void k_ln2(const float* __restrict__ r,
    const float* __restrict__ w, const float* __restrict__ b, float* __restrict__ h2) {
  int row = blockIdx.x;
  int tid = threadIdx.x;
  float v[3]; float sum = 0.f;
#pragma unroll
  for (int i = 0; i < 3; ++i) { v[i] = r[(size_t)row * CHN + tid + i * 64]; sum += v[i]; }
  for (int off = 32; off > 0; off >>= 1) sum += __shfl_down(sum, off);
  sum = __shfl(sum, 0);
  float mu = sum / 192.f;
  float sq = 0.f;
#pragma unroll
  for (int i = 0; i < 3; ++i) { float d = v[i] - mu; sq += d * d; }
  for (int off = 32; off > 0; off >>= 1) sq += __shfl_down(sq, off);
  sq = __shfl(sq, 0);
  float rs = rsqrtf(sq / 192.f + 1e-5f);
#pragma unroll
  for (int i = 0; i < 3; ++i) {
    int c = tid + i * 64;
    h2[(size_t)row * CHN + c] = (v[i] - mu) * rs * w[c] + b[c];
  }
}

// ---------------- K15: out[b,c,t] = resid[b,t,c] + f2[b,t,c]  (f32 out)
__global__ void k_out(const float* __restrict__ r, const float* __restrict__ f,
                      float* __restrict__ out) {
  __shared__ float s[32][33];
  int bb = blockIdx.z; int c0 = blockIdx.y * 32; int t0 = blockIdx.x * 32;
  int tx = threadIdx.x, ty = threadIdx.y;
  for (int i = 0; i < 4; ++i) {
    size_t o = ((size_t)bb * LEN + t0 + ty + i * 8) * CHN + c0 + tx;
    s[tx][ty + i * 8] = r[o] + f[o];
  }
  __syncthreads();
  for (int i = 0; i < 4; ++i)
    out[((size_t)bb * CHN + c0 + ty + i * 8) * LEN + t0 + tx] = s[ty + i * 8][tx];
}

extern "C" void kernel_launch(void* const* d_in, const int* in_sizes, int n_in,
                              void* d_out, int out_size, void* d_ws, size_t ws_size,
                              hipStream_t stream) {
  const float* x     = (const float*)d_in[0];
  const float* n1w   = (const float*)d_in[1];
  const float* n1b   = (const float*)d_in[2];
  const float* win   = (const float*)d_in[3];
  const float* cw    = (const float*)d_in[4];
  const float* cb    = (const float*)d_in[5];
  const float* dtbw  = (const float*)d_in[6];
  const float* alog  = (const float*)d_in[7];
  const float* dskip = (const float*)d_in[8];
  const float* snw   = (const float*)d_in[9];
  const float* wout  = (const float*)d_in[10];
  const float* n2w   = (const float*)d_in[11];
  const float* n2b   = (const float*)d_in[12];
  const float* w1    = (const float*)d_in[13];
  const float* b1    = (const float*)d_in[14];
  const float* w2    = (const float*)d_in[15];
  const float* b2    = (const float*)d_in[16];
  float* out = (float*)d_out;

  int g = 4;
  for (;;) {
    size_t S_BLC = (size_t)g * LEN * CHN;
    size_t S_ZX  = (size_t)g * LEN * DIP;
    size_t S_DT  = (size_t)g * LEN * NHEAD;
    size_t S_XBC = (size_t)g * LEN * 512;
    size_t S_Y   = (size_t)g * LEN * DI;
    size_t S_ST  = (size_t)g * NCHK * NHEAD * 4096;
    size_t TOTAL = 2 * S_BLC + S_ZX + S_DT + S_XBC + S_Y + 2 * S_ST + 768;
    if (TOTAL * 4 <= ws_size) break;
    if (g == 1) return;
    g >>= 1;
  }

  const size_t S_BLC = (size_t)g * LEN * CHN;
  const size_t S_ZX  = (size_t)g * LEN * DIP;
  const size_t S_DT  = (size_t)g * LEN * NHEAD;
  const size_t S_XBC = (size_t)g * LEN * 512;
  const size_t S_Y   = (size_t)g * LEN * DI;
  const size_t S_ST  = (size_t)g * NCHK * NHEAD * 4096;

  float* ws   = (float*)d_ws;
  float* h1   = ws;
  float* U    = ws + S_BLC;
  float* gn   = ws;                          // reuse h1+U after in_proj+dt (2*S_BLC == S_Y)
  float* zx   = ws + 2 * S_BLC;
  float* h2   = zx;                          // reuse zx after gate
  float* f1   = zx + S_BLC;
  float* f2   = zx + S_BLC + S_Y;
  float* dtb  = zx + S_ZX;
  float* xbc  = dtb + S_DT;
  float* m_   = xbc;                         // reuse xbc after ssd2
  float* resid= xbc + S_BLC;
  float* yb   = xbc + S_XBC;
  float* st   = yb + S_Y;
  float* si   = st + S_ST;
  float* at   = si + S_ST;

  const int M = g * LEN;

  for (int b0 = 0; b0 < BATCH; b0 += g) {
    const float* xg  = x   + (size_t)b0 * CHN * LEN;
    float*       og  = out + (size_t)b0 * CHN * LEN;

    // 1. LN1 (transposing)
    k_ln1<<<dim3(LEN / 32, g), 256, 0, stream>>>(xg, n1w, n1b, h1);
    // 2. build u
    k_make_u<<<dim3(LEN / 32, CHN / 32, g), dim3(32, 8), 0, stream>>>(h1, U);
    // 3. in_proj GEMM (bf16 MFMA): cols 0..895 only; dt cols done exactly in k_dt2
    gemm_mfma<0><<<dim3(896 / 64, M / 128), 256, 0, stream>>>(
        U, win, nullptr, zx, M, 896, CHN, DIP);
    // 4. dt (exact f32 from U)
    k_dt2<<<dim3(M / 4), 256, 0, stream>>>(U, win, dtbw, dtb);
    // 5. conv + silu
    k_conv<<<dim3((M * 512 + 255) / 256), 256, 0, stream>>>(zx, cw, cb, xbc, M * 512);
    // 6. SSD intra-chunk
    k_ssd1<<<dim3(NCHK, NHEAD, g), 256, 0, stream>>>(xbc, dtb, alog, yb, st, at);
    // 7. inter-chunk scan
    k_scan<<<dim3(NHEAD, g), 256, 0, stream>>>(st, at, si);
    // 8. SSD off-diagonal + skip
    k_ssd2<<<dim3(NCHK, NHEAD, g), 256, 0, stream>>>(xbc, dtb, alog, dskip, si, yb);
    // 9. gate + RMSNorm
    k_gate<<<dim3(M), 128, 0, stream>>>(yb, zx, snw, gn);
    // 10. out_proj GEMM (bf16 MFMA): (M x 384)@(384 x 192)
    gemm_mfma<0><<<dim3(CHN / 64, M / 128), 256, 0, stream>>>(
        gn, wout, nullptr, m_, M, CHN, DI, CHN);
    // 11. residual 1
    k_resid<<<dim3(LEN / 32, CHN / 32, g), dim3(32, 8), 0, stream>>>(xg, m_, resid);
    // 12. LN2
    k_ln2<<<dim3(M), 64, 0, stream>>>(resid, n2w, n2b, h2);
    // 13. FFN1 + gelu (bf16 MFMA)
    gemm_mfma<1><<<dim3(DI / 64, M / 128), 256, 0, stream>>>(
        h2, w1, b1, f1, M, DI, CHN, DI);
    // 14. FFN2 + bias (bf16 MFMA)
    gemm_mfma<2><<<dim3(CHN / 64, M / 128), 256, 0, stream>>>(
        f1, w2, b2, f2, M, CHN, DI, CHN);
    // 15. final residual + transpose
    k_out<<<dim3(LEN / 32, CHN / 32, g), dim3(32, 8), 0, stream>>>(resid, f2, og);
  }
}

// Round 7
// 887.869 us; speedup vs baseline: 3.7118x; 1.0144x over previous
//
#include <hip/hip_runtime.h>
#include <hip/hip_bf16.h>

#define BATCH 8
#define CHN   192      // d_model
#define LEN   4096     // H*W tokens
#define DIP   902      // in_proj out dim
#define DI    384      // d_inner
#define NHEAD 6
#define HDIM  64
#define DST   64       // d_state
#define NCHK  16       // chunks (LEN/256)

typedef __attribute__((ext_vector_type(8))) short short8;
typedef __attribute__((ext_vector_type(4))) float f32x4;

__device__ __forceinline__ short f2b(float f) {
  unsigned u = __builtin_bit_cast(unsigned, f);
  unsigned r = (u + 0x7FFFu + ((u >> 16) & 1u)) >> 16;  // round-to-nearest-even
  return (short)r;
}

// ---------------- K1: transposing LayerNorm1: x (g,192,L) f32 -> h1 (g,L,192) f32
__global__ __launch_bounds__(256) void k_ln1(const float* __restrict__ x,
    const float* __restrict__ w, const float* __restrict__ b, float* __restrict__ h1) {
  __shared__ float s[192][33];
  __shared__ float red[2][32][8];
  __shared__ float mu_s[32], rs_s[32];
  int bb = blockIdx.y;
  int t0 = blockIdx.x * 32;
  int tid = threadIdx.x;
  for (int i = 0; i < 24; ++i) {
    int idx = tid + i * 256;            // 192*32 = 6144
    int c = idx >> 5, tt = idx & 31;
    s[c][tt] = x[((size_t)bb * CHN + c) * LEN + t0 + tt];
  }
  __syncthreads();
  int tok = tid & 31, part = tid >> 5;
  float sum = 0.f, sq = 0.f;
  for (int c = part * 24; c < part * 24 + 24; ++c) { float v = s[c][tok]; sum += v; sq += v * v; }
  red[0][tok][part] = sum; red[1][tok][part] = sq;
  __syncthreads();
  if (tid < 32) {
    float su = 0.f, qq = 0.f;
    for (int p = 0; p < 8; ++p) { su += red[0][tid][p]; qq += red[1][tid][p]; }
    float mu = su / 192.f;
    float var = qq / 192.f - mu * mu;
    mu_s[tid] = mu; rs_s[tid] = rsqrtf(var + 1e-5f);
  }
  __syncthreads();
  for (int i = 0; i < 24; ++i) {
    int idx = tid + i * 256;
    int c = idx % 192, tt = idx / 192;
    float v = (s[c][tt] - mu_s[tt]) * rs_s[tt] * w[c] + b[c];
    h1[((size_t)bb * LEN + t0 + tt) * CHN + c] = v;
  }
}

// ---------------- K2: u[b,l,c2] = h1_flat[b][c2*LEN + l]
__global__ void k_make_u(const float* __restrict__ h1, float* __restrict__ U) {
  __shared__ float s[32][33];
  int bb = blockIdx.z;
  int c0 = blockIdx.y * 32;
  int l0 = blockIdx.x * 32;
  int tx = threadIdx.x, ty = threadIdx.y;
  const float* src = h1 + (size_t)bb * (CHN * LEN);
  for (int i = 0; i < 4; ++i)
    s[ty + i * 8][tx] = src[(size_t)(c0 + ty + i * 8) * LEN + l0 + tx];
  __syncthreads();
  float* dst = U + (size_t)bb * (CHN * LEN);
  for (int i = 0; i < 4; ++i)
    dst[(size_t)(l0 + ty + i * 8) * CHN + c0 + tx] = s[tx][ty + i * 8];
}

// ---------------- MFMA GEMM: C[M,N](f32,ldc) = A[M,K](f32->bf16) @ W[N,K]^T(f32->bf16)
// BM=128, BN=64, BK=64. 4 waves, each 64(m)x32(n): 4x2 16x16 MFMA tiles.
template <int EPI>
__global__ __launch_bounds__(256) void gemm_mfma(const float* __restrict__ A,
    const float* __restrict__ W, const float* __restrict__ bias,
    float* __restrict__ C, int M, int N, int K, int ldc) {
  __shared__ short Al[128 * 64];  // row stride 128 B
  __shared__ short Wl[64 * 64];
  int m0 = blockIdx.y * 128, n0 = blockIdx.x * 64;
  int tid = threadIdx.x;
  int lane = tid & 63, wv = tid >> 6;
  int wm = (wv >> 1) * 64, wn = (wv & 1) * 32;
  int l15 = lane & 15, l4 = lane >> 4;
  f32x4 acc[4][2] = {};

  int ra = tid >> 1, ca = (tid & 1) * 32;
  int rw = tid >> 2, cw = (tid & 3) * 16;
  char* ArowL = (char*)Al + ra * 128;
  char* WrowL = (char*)Wl + rw * 128;
  int rxa = (ra & 7) << 4, rxw = (rw & 7) << 4;

  for (int k0 = 0; k0 < K; k0 += 64) {
    const float* Ag = A + (size_t)(m0 + ra) * K + k0 + ca;
    const float* Wg = W + (size_t)(n0 + rw) * K + k0 + cw;
#pragma unroll
    for (int q = 0; q < 4; ++q) {
      float4 v0 = *(const float4*)(Ag + q * 8);
      float4 v1 = *(const float4*)(Ag + q * 8 + 4);
      short8 pk;
      pk[0] = f2b(v0.x); pk[1] = f2b(v0.y); pk[2] = f2b(v0.z); pk[3] = f2b(v0.w);
      pk[4] = f2b(v1.x); pk[5] = f2b(v1.y); pk[6] = f2b(v1.z); pk[7] = f2b(v1.w);
      *(short8*)(ArowL + (((ca + q * 8) * 2) ^ rxa)) = pk;
    }
#pragma unroll
    for (int q = 0; q < 2; ++q) {
      float4 v0 = *(const float4*)(Wg + q * 8);
      float4 v1 = *(const float4*)(Wg + q * 8 + 4);
      short8 pk;
      pk[0] = f2b(v0.x); pk[1] = f2b(v0.y); pk[2] = f2b(v0.z); pk[3] = f2b(v0.w);
      pk[4] = f2b(v1.x); pk[5] = f2b(v1.y); pk[6] = f2b(v1.z); pk[7] = f2b(v1.w);
      *(short8*)(WrowL + (((cw + q * 8) * 2) ^ rxw)) = pk;
    }
    __syncthreads();
#pragma unroll
    for (int ks = 0; ks < 64; ks += 32) {
      short8 af[4], wf[2];
#pragma unroll
      for (int mf = 0; mf < 4; ++mf) {
        int rr = wm + mf * 16 + l15;
        af[mf] = *(const short8*)((const char*)Al + rr * 128 +
                                  (((ks + l4 * 8) * 2) ^ ((rr & 7) << 4)));
      }
#pragma unroll
      for (int nf = 0; nf < 2; ++nf) {
        int rr = wn + nf * 16 + l15;
        wf[nf] = *(const short8*)((const char*)Wl + rr * 128 +
                                  (((ks + l4 * 8) * 2) ^ ((rr & 7) << 4)));
      }
#pragma unroll
      for (int mf = 0; mf < 4; ++mf)
#pragma unroll
        for (int nf = 0; nf < 2; ++nf)
          acc[mf][nf] = __builtin_amdgcn_mfma_f32_16x16x32_bf16(
              af[mf], wf[nf], acc[mf][nf], 0, 0, 0);
    }
    __syncthreads();
  }
#pragma unroll
  for (int mf = 0; mf < 4; ++mf) {
#pragma unroll
    for (int nf = 0; nf < 2; ++nf) {
      int col = n0 + wn + nf * 16 + l15;
      float bv = (EPI >= 1) ? bias[col] : 0.f;
#pragma unroll
      for (int reg = 0; reg < 4; ++reg) {
        int row = m0 + wm + mf * 16 + l4 * 4 + reg;
        float v = acc[mf][nf][reg];
        if (EPI >= 1) v += bv;
        if (EPI == 1) v = 0.5f * v * (1.f + erff(v * 0.70710678118f));
        C[(size_t)row * ldc + col] = v;
      }
    }
  }
}

// ---------------- K4: dt computed EXACTLY in f32 from U
__global__ __launch_bounds__(256) void k_dt2(const float* __restrict__ U,
    const float* __restrict__ win, const float* __restrict__ dt_bias,
    float* __restrict__ dtb) {
  __shared__ float Wl[6][192];
  int tid = threadIdx.x;
  for (int i = tid; i < 6 * 192; i += 256)
    Wl[i / 192][i % 192] = win[(size_t)(896 + i / 192) * 192 + (i % 192)];
  __syncthreads();
  int lane = tid & 63, wv = tid >> 6;
  int row = blockIdx.x * 4 + wv;
  float u0 = U[(size_t)row * 192 + lane];
  float u1 = U[(size_t)row * 192 + lane + 64];
  float u2 = U[(size_t)row * 192 + lane + 128];
  float acc[6];
#pragma unroll
  for (int h = 0; h < 6; ++h) {
    float p = u0 * Wl[h][lane] + u1 * Wl[h][lane + 64] + u2 * Wl[h][lane + 128];
    for (int off = 32; off > 0; off >>= 1) p += __shfl_down(p, off);
    acc[h] = p;
  }
  if (lane == 0) {
#pragma unroll
    for (int h = 0; h < 6; ++h) {
      float v = acc[h] + dt_bias[h];
      dtb[(size_t)row * NHEAD + h] = (v > 20.f) ? v : log1pf(expf(v));
    }
  }
}

// ---------------- K5: causal depthwise conv(4) + bias + silu -> xbc (g,L,512)
__global__ void k_conv(const float* __restrict__ zx, const float* __restrict__ cw,
                       const float* __restrict__ cb, float* __restrict__ xbc, int total) {
  int idx = blockIdx.x * 256 + threadIdx.x;
  if (idx >= total) return;
  int ch = idx & 511; int l = (idx >> 9) & (LEN - 1); int bb = idx >> 21;
  float acc = cb[ch];
#pragma unroll
  for (int k = 0; k < 4; ++k) {
    int ll = l - 3 + k;
    if (ll >= 0) acc += zx[((size_t)bb * LEN + ll) * DIP + 384 + ch] * cw[ch * 4 + k];
  }
  xbc[idx] = acc / (1.f + expf(-acc));
}

// ---------------- K6: SSD intra-chunk, split per t-panel.
// block = (cch*4+tp, h, bb). Rotation-swizzled transposed tiles:
// element [c][r] stored at col (r + 4*(c>>2)) & 63  -> conflict-free scalar writes.
__global__ __launch_bounds__(256) void k_ssd1(const float* __restrict__ xbc,
    const float* __restrict__ dtb, const float* __restrict__ A_log,
    float* __restrict__ y, float* __restrict__ states, float* __restrict__ Atot) {
  int cchq = blockIdx.x;
  int cch = cchq >> 2, tp = cchq & 3;
  int h = blockIdx.y, bb = blockIdx.z;
  int tid = threadIdx.x;
  int tx = tid & 15, ty = tid >> 4;
  __shared__ float sA[256];
  __shared__ float sE[256];
  __shared__ float CpT[64][68];   // [n][t'] rotated
  __shared__ float BtT[64][68];   // [n][s'] rotated
  __shared__ float Xt [64][68];   // [s][p] plain
  __shared__ float SpT[64][68];   // [s][t] plain
  size_t rowbase = (size_t)bb * LEN + cch * 256;
  float Ah = -expf(A_log[h]);
  {
    float a = dtb[(rowbase + tid) * NHEAD + h] * Ah;
    sA[tid] = a;
    __syncthreads();
    for (int off = 1; off < 256; off <<= 1) {
      float v = (tid >= off) ? sA[tid - off] : 0.f;
      __syncthreads();
      sA[tid] += v;
      __syncthreads();
    }
  }
  float Atot_v = sA[255];
  sE[tid] = expf(Atot_v - sA[tid]);
  if (tp == 0 && tid == 0) Atot[((size_t)bb * NCHK + cch) * NHEAD + h] = Atot_v;

  // stage C panel (transposed+rotated)
#pragma unroll
  for (int i = 0; i < 4; ++i) {
    int idx = tid + i * 256;
    int r = idx >> 4, c0 = (idx & 15) * 4;
    float4 v = *(const float4*)&xbc[(rowbase + tp * 64 + r) * 512 + 448 + c0];
    int col = (r + c0) & 63;
    CpT[c0 + 0][col] = v.x;
    CpT[c0 + 1][col] = v.y;
    CpT[c0 + 2][col] = v.z;
    CpT[c0 + 3][col] = v.w;
  }

  float yacc[4][4] = {};
  float sacc[4][4] = {};
  for (int st = 0; st <= tp; ++st) {
    __syncthreads();   // protect BtT/Xt restage vs prior readers; CpT staged
#pragma unroll
    for (int i = 0; i < 4; ++i) {
      int idx = tid + i * 256;
      int r = idx >> 4, c0 = (idx & 15) * 4;
      size_t grow = (size_t)(rowbase + st * 64 + r) * 512;
      float4 bv = *(const float4*)&xbc[grow + 384 + c0];
      int col = (r + c0) & 63;
      BtT[c0 + 0][col] = bv.x;
      BtT[c0 + 1][col] = bv.y;
      BtT[c0 + 2][col] = bv.z;
      BtT[c0 + 3][col] = bv.w;
      float dtv = dtb[(rowbase + st * 64 + r) * NHEAD + h];
      float4 xv = *(const float4*)&xbc[grow + h * 64 + c0];
      xv.x *= dtv; xv.y *= dtv; xv.z *= dtv; xv.w *= dtv;
      *(float4*)&Xt[r][c0] = xv;
    }
    __syncthreads();
    // phase 1: p1[i][j] = dot(C[tb+i], B[sb+j]) over n
    float p1[4][4] = {};
#pragma unroll 8
    for (int n = 0; n < 64; ++n) {
      int rot = n & ~3;
      float4 cv = *(const float4*)&CpT[n][(ty * 4 + rot) & 63];
      float4 bv = *(const float4*)&BtT[n][(tx * 4 + rot) & 63];
      float ci[4] = {cv.x, cv.y, cv.z, cv.w};
      float bj[4] = {bv.x, bv.y, bv.z, bv.w};
#pragma unroll
      for (int i = 0; i < 4; ++i)
#pragma unroll
        for (int j = 0; j < 4; ++j) p1[i][j] += ci[i] * bj[j];
    }
    // scale + causal mask, write SpT[s][t]
    {
      int tb = tp * 64 + ty * 4;
      int sb = st * 64 + tx * 4;
      float At[4];
#pragma unroll
      for (int i = 0; i < 4; ++i) At[i] = sA[tb + i];
#pragma unroll
      for (int j = 0; j < 4; ++j) {
        int sg = sb + j;
        float As = sA[sg];
        float4 o;
        o.x = (sg <= tb + 0) ? expf(At[0] - As) * p1[0][j] : 0.f;
        o.y = (sg <= tb + 1) ? expf(At[1] - As) * p1[1][j] : 0.f;
        o.z = (sg <= tb + 2) ? expf(At[2] - As) * p1[2][j] : 0.f;
        o.w = (sg <= tb + 3) ? expf(At[3] - As) * p1[3][j] : 0.f;
        *(float4*)&SpT[tx * 4 + j][ty * 4] = o;
      }
    }
    // chunk-states accumulation: only tp==3 block (covers every s-tile once)
    if (tp == 3) {
#pragma unroll 4
      for (int s = 0; s < 64; s += 4) {
        int colb = (s + tx * 4) & 63;
        float4 b0 = *(const float4*)&BtT[tx * 4 + 0][colb];
        float4 b1 = *(const float4*)&BtT[tx * 4 + 1][colb];
        float4 b2 = *(const float4*)&BtT[tx * 4 + 2][colb];
        float4 b3 = *(const float4*)&BtT[tx * 4 + 3][colb];
        float bw[4][4] = {{b0.x, b0.y, b0.z, b0.w},
                          {b1.x, b1.y, b1.z, b1.w},
                          {b2.x, b2.y, b2.z, b2.w},
                          {b3.x, b3.y, b3.z, b3.w}};
        float xw[4][4];
#pragma unroll
        for (int ss = 0; ss < 4; ++ss) {
          float e = sE[st * 64 + s + ss];
          float4 xv = *(const float4*)&Xt[s + ss][ty * 4];
          xw[ss][0] = xv.x * e; xw[ss][1] = xv.y * e;
          xw[ss][2] = xv.z * e; xw[ss][3] = xv.w * e;
        }
#pragma unroll
        for (int i = 0; i < 4; ++i)
#pragma unroll
          for (int j = 0; j < 4; ++j)
            sacc[i][j] += xw[0][i] * bw[j][0] + xw[1][i] * bw[j][1]
                        + xw[2][i] * bw[j][2] + xw[3][i] * bw[j][3];
      }
    }
    __syncthreads();  // SpT visible
    // phase 2: yacc[i][j] += sum_s SpT[s][tb+i] * Xt[s][p]
#pragma unroll 8
    for (int s = 0; s < 64; ++s) {
      float4 sv = *(const float4*)&SpT[s][ty * 4];
      float4 xv = *(const float4*)&Xt[s][tx * 4];
      float si_[4] = {sv.x, sv.y, sv.z, sv.w};
      float xj[4] = {xv.x, xv.y, xv.z, xv.w};
#pragma unroll
      for (int i = 0; i < 4; ++i)
#pragma unroll
        for (int j = 0; j < 4; ++j) yacc[i][j] += si_[i] * xj[j];
    }
  }
  // write Y_diag panel
#pragma unroll
  for (int i = 0; i < 4; ++i) {
    float4 o = {yacc[i][0], yacc[i][1], yacc[i][2], yacc[i][3]};
    *(float4*)&y[(rowbase + tp * 64 + ty * 4 + i) * DI + h * 64 + tx * 4] = o;
  }
  if (tp == 3) {
    size_t stbase = (((size_t)bb * NCHK + cch) * NHEAD + h) * 4096;
#pragma unroll
    for (int i = 0; i < 4; ++i) {
      float4 o = {sacc[i][0], sacc[i][1], sacc[i][2], sacc[i][3]};
      *(float4*)&states[stbase + (ty * 4 + i) * 64 + tx * 4] = o;
    }
  }
}

// ---------------- K7: inter-chunk scan (sequential over 16 chunks)
__global__ void k_scan(const float* __restrict__ states, const float* __restrict__ Atot,
                       float* __restrict__ Sin) {
  int h = blockIdx.x, bb = blockIdx.y;
  int t = threadIdx.x;
  float S[16];
#pragma unroll
  for (int i = 0; i < 16; ++i) S[i] = 0.f;
  for (int z = 0; z < NCHK; ++z) {
    size_t base = (((size_t)bb * NCHK + z) * NHEAD + h) * 4096 + t * 16;
#pragma unroll
    for (int i = 0; i < 16; ++i) Sin[base + i] = S[i];
    float az = expf(Atot[((size_t)bb * NCHK + z) * NHEAD + h]);
#pragma unroll
    for (int i = 0; i < 16; ++i) S[i] = S[i] * az + states[base + i];
  }
}

// ---------------- K8: y += Y_off + xs*D_skip  (register-tiled, per t-panel)
__global__ __launch_bounds__(256) void k_ssd2(const float* __restrict__ xbc,
    const float* __restrict__ dtb, const float* __restrict__ A_log,
    const float* __restrict__ Dskip, const float* __restrict__ Sin, float* __restrict__ y) {
  int cchq = blockIdx.x;
  int cch = cchq >> 2, tp = cchq & 3;
  int h = blockIdx.y, bb = blockIdx.z;
  int tid = threadIdx.x;
  int tx = tid & 15, ty = tid >> 4;
  __shared__ float sA[256];
  __shared__ float CpT[64][68];   // [n][t'] rotated
  __shared__ float SnT[64][68];   // [n][p'] rotated
  size_t rowbase = (size_t)bb * LEN + cch * 256;
  float Ah = -expf(A_log[h]);
  sA[tid] = dtb[(rowbase + tid) * NHEAD + h] * Ah;
  __syncthreads();
  for (int off = 1; off < 256; off <<= 1) {
    float v = (tid >= off) ? sA[tid - off] : 0.f;
    __syncthreads();
    sA[tid] += v;
    __syncthreads();
  }
  size_t sinbase = (((size_t)bb * NCHK + cch) * NHEAD + h) * 4096;
#pragma unroll
  for (int i = 0; i < 4; ++i) {
    int idx = tid + i * 256;
    int r = idx >> 4, c0 = (idx & 15) * 4;
    int col = (r + c0) & 63;
    float4 v = *(const float4*)&xbc[(rowbase + tp * 64 + r) * 512 + 448 + c0];
    CpT[c0 + 0][col] = v.x;
    CpT[c0 + 1][col] = v.y;
    CpT[c0 + 2][col] = v.z;
    CpT[c0 + 3][col] = v.w;
    float4 s4 = *(const float4*)&Sin[sinbase + (size_t)r * 64 + c0];  // r = p
    SnT[c0 + 0][col] = s4.x;
    SnT[c0 + 1][col] = s4.y;
    SnT[c0 + 2][col] = s4.z;
    SnT[c0 + 3][col] = s4.w;
  }
  __syncthreads();
  float acc[4][4] = {};
#pragma unroll 8
  for (int n = 0; n < 64; ++n) {
    int rot = n & ~3;
    float4 cv = *(const float4*)&CpT[n][(ty * 4 + rot) & 63];
    float4 sv = *(const float4*)&SnT[n][(tx * 4 + rot) & 63];
    float ci[4] = {cv.x, cv.y, cv.z, cv.w};
    float pj[4] = {sv.x, sv.y, sv.z, sv.w};
#pragma unroll
    for (int i = 0; i < 4; ++i)
#pragma unroll
      for (int j = 0; j < 4; ++j) acc[i][j] += ci[i] * pj[j];
  }
  float Dh = Dskip[h];
#pragma unroll
  for (int i = 0; i < 4; ++i) {
    int t = tp * 64 + ty * 4 + i;
    float et = expf(sA[t]);
    size_t grow = (size_t)(rowbase + t);
    float4 xv = *(const float4*)&xbc[grow * 512 + h * 64 + tx * 4];
    float* yp = &y[grow * DI + h * 64 + tx * 4];
    float4 yv = *(const float4*)yp;
    yv.x += et * acc[i][0] + Dh * xv.x;
    yv.y += et * acc[i][1] + Dh * xv.y;
    yv.z += et * acc[i][2] + Dh * xv.z;
    yv.w += et * acc[i][3] + Dh * xv.w;
    *(float4*)yp = yv;
  }
}

// ---------------- K9: g = y*silu(z); RMSNorm(384) * ssm_norm_w -> gn
__global__ __launch_bounds__(128) void k_gate(const float* __restrict__ y,
    const float* __restrict__ zx, const float* __restrict__ nw, float* __restrict__ gn) {
  int row = blockIdx.x;
  int tid = threadIdx.x;
  float g[3]; float sq = 0.f;
#pragma unroll
  for (int i = 0; i < 3; ++i) {
    int d = tid + i * 128;
    float z = zx[(size_t)row * DIP + d];
    float gg = y[(size_t)row * DI + d] * (z / (1.f + expf(-z)));
    g[i] = gg; sq += gg * gg;
  }
  for (int off = 32; off > 0; off >>= 1) sq += __shfl_down(sq, off);
  __shared__ float wsum[2];
  if ((tid & 63) == 0) wsum[tid >> 6] = sq;
  __syncthreads();
  float rs = rsqrtf((wsum[0] + wsum[1]) / 384.f + 1e-5f);
#pragma unroll
  for (int i = 0; i < 3; ++i) {
    int d = tid + i * 128;
    gn[(size_t)row * DI + d] = g[i] * rs * nw[d];
  }
}

// ---------------- K11: resid[b,t,c] = x[b,c,t] + m[b,t,c]
__global__ void k_resid(const float* __restrict__ x, const float* __restrict__ m,
                        float* __restrict__ r) {
  __shared__ float s[32][33];
  int bb = blockIdx.z; int c0 = blockIdx.y * 32; int t0 = blockIdx.x * 32;
  int tx = threadIdx.x, ty = threadIdx.y;
  for (int i = 0; i < 4; ++i)
    s[ty + i * 8][tx] = x[((size_t)bb * CHN + c0 + ty + i * 8) * LEN + t0 + tx];
  __syncthreads();
  for (int i = 0; i < 4; ++i) {
    size_t o = ((size_t)bb * LEN + t0 + ty + i * 8) * CHN + c0 + tx;
    r[o] = s[tx][ty + i * 8] + m[o];
  }
}

// ---------------- K12: plain LayerNorm over 192 (rowwise)
__global__ __launch_bounds__(64) void k_ln2(const float* __restrict__ r,
    const float* __restrict__ w, const float* __restrict__ b, float* __restrict__ h2) {
  int row = blockIdx.x;
  int tid = threadIdx.x;
  float v[3]; float sum = 0.f;
#pragma unroll
  for (int i = 0; i < 3; ++i) { v[i] = r[(size_t)row * CHN + tid + i * 64]; sum += v[i]; }
  for (int off = 32; off > 0; off >>= 1) sum += __shfl_down(sum, off);
  sum = __shfl(sum, 0);
  float mu = sum / 192.f;
  float sq = 0.f;
#pragma unroll
  for (int i = 0; i < 3; ++i) { float d = v[i] - mu; sq += d * d; }
  for (int off = 32; off > 0; off >>= 1) sq += __shfl_down(sq, off);
  sq = __shfl(sq, 0);
  float rs = rsqrtf(sq / 192.f + 1e-5f);
#pragma unroll
  for (int i = 0; i < 3; ++i) {
    int c = tid + i * 64;
    h2[(size_t)row * CHN + c] = (v[i] - mu) * rs * w[c] + b[c];
  }
}

// ---------------- K15: out[b,c,t] = resid[b,t,c] + f2[b,t,c]  (f32 out)
__global__ void k_out(const float* __restrict__ r, const float* __restrict__ f,
                      float* __restrict__ out) {
  __shared__ float s[32][33];
  int bb = blockIdx.z; int c0 = blockIdx.y * 32; int t0 = blockIdx.x * 32;
  int tx = threadIdx.x, ty = threadIdx.y;
  for (int i = 0; i < 4; ++i) {
    size_t o = ((size_t)bb * LEN + t0 + ty + i * 8) * CHN + c0 + tx;
    s[tx][ty + i * 8] = r[o] + f[o];
  }
  __syncthreads();
  for (int i = 0; i < 4; ++i)
    out[((size_t)bb * CHN + c0 + ty + i * 8) * LEN + t0 + tx] = s[ty + i * 8][tx];
}

extern "C" void kernel_launch(void* const* d_in, const int* in_sizes, int n_in,
                              void* d_out, int out_size, void* d_ws, size_t ws_size,
                              hipStream_t stream) {
  const float* x     = (const float*)d_in[0];
  const float* n1w   = (const float*)d_in[1];
  const float* n1b   = (const float*)d_in[2];
  const float* win   = (const float*)d_in[3];
  const float* cw    = (const float*)d_in[4];
  const float* cb    = (const float*)d_in[5];
  const float* dtbw  = (const float*)d_in[6];
  const float* alog  = (const float*)d_in[7];
  const float* dskip = (const float*)d_in[8];
  const float* snw   = (const float*)d_in[9];
  const float* wout  = (const float*)d_in[10];
  const float* n2w   = (const float*)d_in[11];
  const float* n2b   = (const float*)d_in[12];
  const float* w1    = (const float*)d_in[13];
  const float* b1    = (const float*)d_in[14];
  const float* w2    = (const float*)d_in[15];
  const float* b2    = (const float*)d_in[16];
  float* out = (float*)d_out;

  int g = 4;
  for (;;) {
    size_t S_BLC = (size_t)g * LEN * CHN;
    size_t S_ZX  = (size_t)g * LEN * DIP;
    size_t S_DT  = (size_t)g * LEN * NHEAD;
    size_t S_XBC = (size_t)g * LEN * 512;
    size_t S_Y   = (size_t)g * LEN * DI;
    size_t S_ST  = (size_t)g * NCHK * NHEAD * 4096;
    size_t TOTAL = 2 * S_BLC + S_ZX + S_DT + S_XBC + S_Y + 2 * S_ST + 768;
    if (TOTAL * 4 <= ws_size) break;
    if (g == 1) return;
    g >>= 1;
  }

  const size_t S_BLC = (size_t)g * LEN * CHN;
  const size_t S_ZX  = (size_t)g * LEN * DIP;
  const size_t S_DT  = (size_t)g * LEN * NHEAD;
  const size_t S_XBC = (size_t)g * LEN * 512;
  const size_t S_Y   = (size_t)g * LEN * DI;
  const size_t S_ST  = (size_t)g * NCHK * NHEAD * 4096;

  float* ws   = (float*)d_ws;
  float* h1   = ws;
  float* U    = ws + S_BLC;
  float* gn   = ws;
  float* zx   = ws + 2 * S_BLC;
  float* h2   = zx;
  float* f1   = zx + S_BLC;
  float* f2   = zx + S_BLC + S_Y;
  float* dtb  = zx + S_ZX;
  float* xbc  = dtb + S_DT;
  float* m_   = xbc;
  float* resid= xbc + S_BLC;
  float* yb   = xbc + S_XBC;
  float* st   = yb + S_Y;
  float* si   = st + S_ST;
  float* at   = si + S_ST;

  const int M = g * LEN;

  for (int b0 = 0; b0 < BATCH; b0 += g) {
    const float* xg  = x   + (size_t)b0 * CHN * LEN;
    float*       og  = out + (size_t)b0 * CHN * LEN;

    k_ln1<<<dim3(LEN / 32, g), 256, 0, stream>>>(xg, n1w, n1b, h1);
    k_make_u<<<dim3(LEN / 32, CHN / 32, g), dim3(32, 8), 0, stream>>>(h1, U);
    gemm_mfma<0><<<dim3(896 / 64, M / 128), 256, 0, stream>>>(
        U, win, nullptr, zx, M, 896, CHN, DIP);
    k_dt2<<<dim3(M / 4), 256, 0, stream>>>(U, win, dtbw, dtb);
    k_conv<<<dim3((M * 512 + 255) / 256), 256, 0, stream>>>(zx, cw, cb, xbc, M * 512);
    // SSD intra-chunk, split per t-panel
    k_ssd1<<<dim3(NCHK * 4, NHEAD, g), 256, 0, stream>>>(xbc, dtb, alog, yb, st, at);
    k_scan<<<dim3(NHEAD, g), 256, 0, stream>>>(st, at, si);
    // SSD off-diagonal + skip, register-tiled per t-panel
    k_ssd2<<<dim3(NCHK * 4, NHEAD, g), 256, 0, stream>>>(xbc, dtb, alog, dskip, si, yb);
    k_gate<<<dim3(M), 128, 0, stream>>>(yb, zx, snw, gn);
    gemm_mfma<0><<<dim3(CHN / 64, M / 128), 256, 0, stream>>>(
        gn, wout, nullptr, m_, M, CHN, DI, CHN);
    k_resid<<<dim3(LEN / 32, CHN / 32, g), dim3(32, 8), 0, stream>>>(xg, m_, resid);
    k_ln2<<<dim3(M), 64, 0, stream>>>(resid, n2w, n2b, h2);
    gemm_mfma<1><<<dim3(DI / 64, M / 128), 256, 0, stream>>>(
        h2, w1, b1, f1, M, DI, CHN, DI);
    gemm_mfma<2><<<dim3(CHN / 64, M / 128), 256, 0, stream>>>(
        f1, w2, b2, f2, M, CHN, DI, CHN);
    k_out<<<dim3(LEN / 32, CHN / 32, g), dim3(32, 8), 0, stream>>>(resid, f2, og);
  }
}

// Round 8
// 618.168 us; speedup vs baseline: 5.3312x; 1.4363x over previous
//
#include <hip/hip_runtime.h>
#include <hip/hip_bf16.h>

#define BATCH 8
#define CHN   192      // d_model
#define LEN   4096     // H*W tokens
#define DIP   902      // in_proj out dim
#define DI    384      // d_inner
#define NHEAD 6
#define HDIM  64
#define DST   64       // d_state
#define NCHK  16       // chunks (LEN/256)

typedef __attribute__((ext_vector_type(8))) short short8;
typedef __attribute__((ext_vector_type(4))) short short4v;
typedef __attribute__((ext_vector_type(4))) float f32x4;

__device__ __forceinline__ short f2b(float f) {
  unsigned u = __builtin_bit_cast(unsigned, f);
  unsigned r = (u + 0x7FFFu + ((u >> 16) & 1u)) >> 16;  // round-to-nearest-even
  return (short)r;
}

// ---------------- K1: transposing LayerNorm1: x (g,192,L) f32 -> h1 (g,L,192) f32
__global__ __launch_bounds__(256) void k_ln1(const float* __restrict__ x,
    const float* __restrict__ w, const float* __restrict__ b, float* __restrict__ h1) {
  __shared__ float s[192][33];
  __shared__ float red[2][32][8];
  __shared__ float mu_s[32], rs_s[32];
  int bb = blockIdx.y;
  int t0 = blockIdx.x * 32;
  int tid = threadIdx.x;
  for (int i = 0; i < 24; ++i) {
    int idx = tid + i * 256;            // 192*32 = 6144
    int c = idx >> 5, tt = idx & 31;
    s[c][tt] = x[((size_t)bb * CHN + c) * LEN + t0 + tt];
  }
  __syncthreads();
  int tok = tid & 31, part = tid >> 5;
  float sum = 0.f, sq = 0.f;
  for (int c = part * 24; c < part * 24 + 24; ++c) { float v = s[c][tok]; sum += v; sq += v * v; }
  red[0][tok][part] = sum; red[1][tok][part] = sq;
  __syncthreads();
  if (tid < 32) {
    float su = 0.f, qq = 0.f;
    for (int p = 0; p < 8; ++p) { su += red[0][tid][p]; qq += red[1][tid][p]; }
    float mu = su / 192.f;
    float var = qq / 192.f - mu * mu;
    mu_s[tid] = mu; rs_s[tid] = rsqrtf(var + 1e-5f);
  }
  __syncthreads();
  for (int i = 0; i < 24; ++i) {
    int idx = tid + i * 256;
    int c = idx % 192, tt = idx / 192;
    float v = (s[c][tt] - mu_s[tt]) * rs_s[tt] * w[c] + b[c];
    h1[((size_t)bb * LEN + t0 + tt) * CHN + c] = v;
  }
}

// ---------------- K2: u[b,l,c2] = h1_flat[b][c2*LEN + l]
__global__ void k_make_u(const float* __restrict__ h1, float* __restrict__ U) {
  __shared__ float s[32][33];
  int bb = blockIdx.z;
  int c0 = blockIdx.y * 32;
  int l0 = blockIdx.x * 32;
  int tx = threadIdx.x, ty = threadIdx.y;
  const float* src = h1 + (size_t)bb * (CHN * LEN);
  for (int i = 0; i < 4; ++i)
    s[ty + i * 8][tx] = src[(size_t)(c0 + ty + i * 8) * LEN + l0 + tx];
  __syncthreads();
  float* dst = U + (size_t)bb * (CHN * LEN);
  for (int i = 0; i < 4; ++i)
    dst[(size_t)(l0 + ty + i * 8) * CHN + c0 + tx] = s[tx][ty + i * 8];
}

// ---------------- MFMA GEMM: C[M,N](f32,ldc) = A[M,K](f32->bf16) @ W[N,K]^T(f32->bf16)
template <int EPI>
__global__ __launch_bounds__(256) void gemm_mfma(const float* __restrict__ A,
    const float* __restrict__ W, const float* __restrict__ bias,
    float* __restrict__ C, int M, int N, int K, int ldc) {
  __shared__ short Al[128 * 64];  // row stride 128 B
  __shared__ short Wl[64 * 64];
  int m0 = blockIdx.y * 128, n0 = blockIdx.x * 64;
  int tid = threadIdx.x;
  int lane = tid & 63, wv = tid >> 6;
  int wm = (wv >> 1) * 64, wn = (wv & 1) * 32;
  int l15 = lane & 15, l4 = lane >> 4;
  f32x4 acc[4][2] = {};

  int ra = tid >> 1, ca = (tid & 1) * 32;
  int rw = tid >> 2, cw = (tid & 3) * 16;
  char* ArowL = (char*)Al + ra * 128;
  char* WrowL = (char*)Wl + rw * 128;
  int rxa = (ra & 7) << 4, rxw = (rw & 7) << 4;

  for (int k0 = 0; k0 < K; k0 += 64) {
    const float* Ag = A + (size_t)(m0 + ra) * K + k0 + ca;
    const float* Wg = W + (size_t)(n0 + rw) * K + k0 + cw;
#pragma unroll
    for (int q = 0; q < 4; ++q) {
      float4 v0 = *(const float4*)(Ag + q * 8);
      float4 v1 = *(const float4*)(Ag + q * 8 + 4);
      short8 pk;
      pk[0] = f2b(v0.x); pk[1] = f2b(v0.y); pk[2] = f2b(v0.z); pk[3] = f2b(v0.w);
      pk[4] = f2b(v1.x); pk[5] = f2b(v1.y); pk[6] = f2b(v1.z); pk[7] = f2b(v1.w);
      *(short8*)(ArowL + (((ca + q * 8) * 2) ^ rxa)) = pk;
    }
#pragma unroll
    for (int q = 0; q < 2; ++q) {
      float4 v0 = *(const float4*)(Wg + q * 8);
      float4 v1 = *(const float4*)(Wg + q * 8 + 4);
      short8 pk;
      pk[0] = f2b(v0.x); pk[1] = f2b(v0.y); pk[2] = f2b(v0.z); pk[3] = f2b(v0.w);
      pk[4] = f2b(v1.x); pk[5] = f2b(v1.y); pk[6] = f2b(v1.z); pk[7] = f2b(v1.w);
      *(short8*)(WrowL + (((cw + q * 8) * 2) ^ rxw)) = pk;
    }
    __syncthreads();
#pragma unroll
    for (int ks = 0; ks < 64; ks += 32) {
      short8 af[4], wf[2];
#pragma unroll
      for (int mf = 0; mf < 4; ++mf) {
        int rr = wm + mf * 16 + l15;
        af[mf] = *(const short8*)((const char*)Al + rr * 128 +
                                  (((ks + l4 * 8) * 2) ^ ((rr & 7) << 4)));
      }
#pragma unroll
      for (int nf = 0; nf < 2; ++nf) {
        int rr = wn + nf * 16 + l15;
        wf[nf] = *(const short8*)((const char*)Wl + rr * 128 +
                                  (((ks + l4 * 8) * 2) ^ ((rr & 7) << 4)));
      }
#pragma unroll
      for (int mf = 0; mf < 4; ++mf)
#pragma unroll
        for (int nf = 0; nf < 2; ++nf)
          acc[mf][nf] = __builtin_amdgcn_mfma_f32_16x16x32_bf16(
              af[mf], wf[nf], acc[mf][nf], 0, 0, 0);
    }
    __syncthreads();
  }
#pragma unroll
  for (int mf = 0; mf < 4; ++mf) {
#pragma unroll
    for (int nf = 0; nf < 2; ++nf) {
      int col = n0 + wn + nf * 16 + l15;
      float bv = (EPI >= 1) ? bias[col] : 0.f;
#pragma unroll
      for (int reg = 0; reg < 4; ++reg) {
        int row = m0 + wm + mf * 16 + l4 * 4 + reg;
        float v = acc[mf][nf][reg];
        if (EPI >= 1) v += bv;
        if (EPI == 1) v = 0.5f * v * (1.f + erff(v * 0.70710678118f));
        C[(size_t)row * ldc + col] = v;
      }
    }
  }
}

// ---------------- K4: dt computed EXACTLY in f32 from U
__global__ __launch_bounds__(256) void k_dt2(const float* __restrict__ U,
    const float* __restrict__ win, const float* __restrict__ dt_bias,
    float* __restrict__ dtb) {
  __shared__ float Wl[6][192];
  int tid = threadIdx.x;
  for (int i = tid; i < 6 * 192; i += 256)
    Wl[i / 192][i % 192] = win[(size_t)(896 + i / 192) * 192 + (i % 192)];
  __syncthreads();
  int lane = tid & 63, wv = tid >> 6;
  int row = blockIdx.x * 4 + wv;
  float u0 = U[(size_t)row * 192 + lane];
  float u1 = U[(size_t)row * 192 + lane + 64];
  float u2 = U[(size_t)row * 192 + lane + 128];
  float acc[6];
#pragma unroll
  for (int h = 0; h < 6; ++h) {
    float p = u0 * Wl[h][lane] + u1 * Wl[h][lane + 64] + u2 * Wl[h][lane + 128];
    for (int off = 32; off > 0; off >>= 1) p += __shfl_down(p, off);
    acc[h] = p;
  }
  if (lane == 0) {
#pragma unroll
    for (int h = 0; h < 6; ++h) {
      float v = acc[h] + dt_bias[h];
      dtb[(size_t)row * NHEAD + h] = (v > 20.f) ? v : log1pf(expf(v));
    }
  }
}

// ---------------- K5: causal depthwise conv(4) + bias + silu -> xbc (g,L,512)
__global__ void k_conv(const float* __restrict__ zx, const float* __restrict__ cw,
                       const float* __restrict__ cb, float* __restrict__ xbc, int total) {
  int idx = blockIdx.x * 256 + threadIdx.x;
  if (idx >= total) return;
  int ch = idx & 511; int l = (idx >> 9) & (LEN - 1); int bb = idx >> 21;
  float acc = cb[ch];
#pragma unroll
  for (int k = 0; k < 4; ++k) {
    int ll = l - 3 + k;
    if (ll >= 0) acc += zx[((size_t)bb * LEN + ll) * DIP + 384 + ch] * cw[ch * 4 + k];
  }
  xbc[idx] = acc / (1.f + expf(-acc));
}

// ---------------- K6: SSD intra-chunk via MFMA. One block per (cch,h,bb), 4 waves.
// Wave w owns t-panel tp=w. Phase1: S^T = mfma(B-rows, C-rows); pack S into
// per-wave Sb[t][s] bf16; Phase2: Y = mfma(X^T-rows, Sb-rows). States:
// mfma((B^T*sE)-rows, X^T-rows). All LDS XOR-swizzled byte^=(row&7)<<4.
__global__ __launch_bounds__(256) void k_ssd1(const float* __restrict__ xbc,
    const float* __restrict__ dtb, const float* __restrict__ A_log,
    float* __restrict__ y, float* __restrict__ states, float* __restrict__ Atot) {
  int cch = blockIdx.x, h = blockIdx.y, bb = blockIdx.z;
  int tid = threadIdx.x;
  int lane = tid & 63, wv = tid >> 6;
  int l15 = lane & 15, l4 = lane >> 4;
  __shared__ float sA[256];
  __shared__ float sE[256];
  __shared__ short Cb[256 * 64];   // [t][n], 128B rows
  __shared__ short Bb[256 * 64];   // [s][n]
  __shared__ short Xt[64 * 256];   // [p][s] = X[s][p]*dt, 512B rows
  __shared__ short SbBt[64 * 256]; // phase1/2: per-wave Sb[64][64]; states: Bt[n][s]
  size_t rowbase = (size_t)bb * LEN + cch * 256;
  float Ah = -expf(A_log[h]);
  {
    float a = dtb[(rowbase + tid) * NHEAD + h] * Ah;
    sA[tid] = a;
    __syncthreads();
    for (int off = 1; off < 256; off <<= 1) {
      float v = (tid >= off) ? sA[tid - off] : 0.f;
      __syncthreads();
      sA[tid] += v;
      __syncthreads();
    }
  }
  float Atot_v = sA[255];
  sE[tid] = __expf(Atot_v - sA[tid]);
  if (tid == 0) Atot[((size_t)bb * NCHK + cch) * NHEAD + h] = Atot_v;

  // stage Cb, Bb (row-major bf16) and Xt (transposed, dt-scaled)
#pragma unroll
  for (int pass = 0; pass < 4; ++pass) {
    int r = (tid >> 2) + pass * 64;
    int cq = (tid & 3) * 16;
    size_t grow = (size_t)(rowbase + r) * 512;
    float dtv = dtb[(rowbase + r) * NHEAD + h];
    int swr = (r & 7) << 4;
#pragma unroll
    for (int q = 0; q < 4; ++q) {
      int c0 = cq + q * 4;
      float4 cv = *(const float4*)&xbc[grow + 448 + c0];
      short4v cp = {f2b(cv.x), f2b(cv.y), f2b(cv.z), f2b(cv.w)};
      *(short4v*)((char*)Cb + r * 128 + ((c0 * 2) ^ swr)) = cp;
      float4 bv = *(const float4*)&xbc[grow + 384 + c0];
      short4v bp = {f2b(bv.x), f2b(bv.y), f2b(bv.z), f2b(bv.w)};
      *(short4v*)((char*)Bb + r * 128 + ((c0 * 2) ^ swr)) = bp;
      float4 xv = *(const float4*)&xbc[grow + h * 64 + c0];
#pragma unroll
      for (int j = 0; j < 4; ++j) {
        float xx = ((const float*)&xv)[j] * dtv;
        int p = c0 + j;
        *(short*)((char*)Xt + p * 512 + ((r * 2) ^ ((p & 7) << 4))) = f2b(xx);
      }
    }
  }
  __syncthreads();

  int tp = wv;
  float sAt[4];
#pragma unroll
  for (int ni = 0; ni < 4; ++ni) sAt[ni] = sA[tp * 64 + ni * 16 + l15];
  f32x4 yacc[4][4] = {};   // [mi over p][ni over t]
  short* Sw = SbBt + wv * 64 * 64;

  for (int st = 0; st <= tp; ++st) {
    // phase 1: S^T tiles (m=s, n=t)
    f32x4 sacc[4][4] = {};
#pragma unroll
    for (int ks = 0; ks < 2; ++ks) {
      short8 afr[4], bfr[4];
#pragma unroll
      for (int mi = 0; mi < 4; ++mi) {
        int rr = st * 64 + mi * 16 + l15;
        afr[mi] = *(const short8*)((const char*)Bb + rr * 128 +
                                   (((ks * 32 + l4 * 8) * 2) ^ ((rr & 7) << 4)));
      }
#pragma unroll
      for (int ni = 0; ni < 4; ++ni) {
        int rr = tp * 64 + ni * 16 + l15;
        bfr[ni] = *(const short8*)((const char*)Cb + rr * 128 +
                                   (((ks * 32 + l4 * 8) * 2) ^ ((rr & 7) << 4)));
      }
#pragma unroll
      for (int mi = 0; mi < 4; ++mi)
#pragma unroll
        for (int ni = 0; ni < 4; ++ni)
          sacc[mi][ni] = __builtin_amdgcn_mfma_f32_16x16x32_bf16(
              afr[mi], bfr[ni], sacc[mi][ni], 0, 0, 0);
    }
    // mask + decay + cvt -> Sb[t][s] (packed 8B writes: 4 consecutive s)
#pragma unroll
    for (int mi = 0; mi < 4; ++mi) {
      float sAs[4];
#pragma unroll
      for (int reg = 0; reg < 4; ++reg) sAs[reg] = sA[st * 64 + mi * 16 + l4 * 4 + reg];
      int sbase = st * 64 + mi * 16 + l4 * 4;
#pragma unroll
      for (int ni = 0; ni < 4; ++ni) {
        int t_loc = ni * 16 + l15;
        int tg = tp * 64 + t_loc;
        float At = sAt[ni];
        short4v pk;
#pragma unroll
        for (int reg = 0; reg < 4; ++reg) {
          float v = (sbase + reg <= tg) ? __expf(At - sAs[reg]) * sacc[mi][ni][reg] : 0.f;
          pk[reg] = f2b(v);
        }
        *(short4v*)((char*)Sw + t_loc * 128 +
                    (((mi * 16 + l4 * 4) * 2) ^ ((t_loc & 7) << 4))) = pk;
      }
    }
    // phase 2: Yacc += X^T @ Sb^T  (m=p, n=t, k=s_loc)
#pragma unroll
    for (int ks = 0; ks < 2; ++ks) {
      short8 afr[4], bfr[4];
#pragma unroll
      for (int mi = 0; mi < 4; ++mi) {
        int rp = mi * 16 + l15;
        int sg = st * 64 + ks * 32 + l4 * 8;
        afr[mi] = *(const short8*)((const char*)Xt + rp * 512 +
                                   ((sg * 2) ^ ((rp & 7) << 4)));
      }
#pragma unroll
      for (int ni = 0; ni < 4; ++ni) {
        int rt = ni * 16 + l15;
        bfr[ni] = *(const short8*)((const char*)Sw + rt * 128 +
                                   (((ks * 32 + l4 * 8) * 2) ^ ((rt & 7) << 4)));
      }
#pragma unroll
      for (int mi = 0; mi < 4; ++mi)
#pragma unroll
        for (int ni = 0; ni < 4; ++ni)
          yacc[mi][ni] = __builtin_amdgcn_mfma_f32_16x16x32_bf16(
              afr[mi], bfr[ni], yacc[mi][ni], 0, 0, 0);
    }
  }
  // write Y panel: lane: t = tp*64+ni*16+l15, p = mi*16+l4*4+reg (float4 over reg)
#pragma unroll
  for (int ni = 0; ni < 4; ++ni) {
    int tg = tp * 64 + ni * 16 + l15;
#pragma unroll
    for (int mi = 0; mi < 4; ++mi) {
      float4 o = {yacc[mi][ni][0], yacc[mi][ni][1], yacc[mi][ni][2], yacc[mi][ni][3]};
      *(float4*)&y[(rowbase + tg) * DI + h * 64 + mi * 16 + l4 * 4] = o;
    }
  }
  __syncthreads();
  // restage SbBt as Bt[n][s] = B[s][n] * sE[s]
#pragma unroll
  for (int pass = 0; pass < 4; ++pass) {
    int r = (tid >> 2) + pass * 64;
    int cq = (tid & 3) * 16;
    size_t grow = (size_t)(rowbase + r) * 512;
    float e = sE[r];
#pragma unroll
    for (int q = 0; q < 4; ++q) {
      float4 bv = *(const float4*)&xbc[grow + 384 + cq + q * 4];
#pragma unroll
      for (int j = 0; j < 4; ++j) {
        int n = cq + q * 4 + j;
        float vv = ((const float*)&bv)[j] * e;
        *(short*)((char*)SbBt + n * 512 + ((r * 2) ^ ((n & 7) << 4))) = f2b(vv);
      }
    }
  }
  __syncthreads();
  // states: wave wv does n-rows [wv*16, wv*16+16): D[m=n][n'=p] = Bt @ Xt^T
  f32x4 stacc[4] = {};
#pragma unroll
  for (int ks = 0; ks < 8; ++ks) {
    int rn = wv * 16 + l15;
    short8 afr = *(const short8*)((const char*)SbBt + rn * 512 +
                                  (((ks * 32 + l4 * 8) * 2) ^ ((rn & 7) << 4)));
    short8 bfr[4];
#pragma unroll
    for (int ni = 0; ni < 4; ++ni) {
      int rp = ni * 16 + l15;
      bfr[ni] = *(const short8*)((const char*)Xt + rp * 512 +
                                 (((ks * 32 + l4 * 8) * 2) ^ ((rp & 7) << 4)));
    }
#pragma unroll
    for (int ni = 0; ni < 4; ++ni)
      stacc[ni] = __builtin_amdgcn_mfma_f32_16x16x32_bf16(afr, bfr[ni], stacc[ni], 0, 0, 0);
  }
  size_t stbase = (((size_t)bb * NCHK + cch) * NHEAD + h) * 4096;
#pragma unroll
  for (int ni = 0; ni < 4; ++ni) {
    int p = ni * 16 + l15;
    float4 o = {stacc[ni][0], stacc[ni][1], stacc[ni][2], stacc[ni][3]};
    *(float4*)&states[stbase + p * 64 + wv * 16 + l4 * 4] = o;
  }
}

// ---------------- K7: inter-chunk scan (sequential over 16 chunks)
__global__ void k_scan(const float* __restrict__ states, const float* __restrict__ Atot,
                       float* __restrict__ Sin) {
  int h = blockIdx.x, bb = blockIdx.y;
  int t = threadIdx.x;
  float S[16];
#pragma unroll
  for (int i = 0; i < 16; ++i) S[i] = 0.f;
  for (int z = 0; z < NCHK; ++z) {
    size_t base = (((size_t)bb * NCHK + z) * NHEAD + h) * 4096 + t * 16;
#pragma unroll
    for (int i = 0; i < 16; ++i) Sin[base + i] = S[i];
    float az = expf(Atot[((size_t)bb * NCHK + z) * NHEAD + h]);
#pragma unroll
    for (int i = 0; i < 16; ++i) S[i] = S[i] * az + states[base + i];
  }
}

// ---------------- K8: y += Y_off + xs*D_skip  (register-tiled, per t-panel)
__global__ __launch_bounds__(256) void k_ssd2(const float* __restrict__ xbc,
    const float* __restrict__ dtb, const float* __restrict__ A_log,
    const float* __restrict__ Dskip, const float* __restrict__ Sin, float* __restrict__ y) {
  int cchq = blockIdx.x;
  int cch = cchq >> 2, tp = cchq & 3;
  int h = blockIdx.y, bb = blockIdx.z;
  int tid = threadIdx.x;
  int tx = tid & 15, ty = tid >> 4;
  __shared__ float sA[256];
  __shared__ float CpT[64][68];   // [n][t'] rotated
  __shared__ float SnT[64][68];   // [n][p'] rotated
  size_t rowbase = (size_t)bb * LEN + cch * 256;
  float Ah = -expf(A_log[h]);
  sA[tid] = dtb[(rowbase + tid) * NHEAD + h] * Ah;
  __syncthreads();
  for (int off = 1; off < 256; off <<= 1) {
    float v = (tid >= off) ? sA[tid - off] : 0.f;
    __syncthreads();
    sA[tid] += v;
    __syncthreads();
  }
  size_t sinbase = (((size_t)bb * NCHK + cch) * NHEAD + h) * 4096;
#pragma unroll
  for (int i = 0; i < 4; ++i) {
    int idx = tid + i * 256;
    int r = idx >> 4, c0 = (idx & 15) * 4;
    int col = (r + c0) & 63;
    float4 v = *(const float4*)&xbc[(rowbase + tp * 64 + r) * 512 + 448 + c0];
    CpT[c0 + 0][col] = v.x;
    CpT[c0 + 1][col] = v.y;
    CpT[c0 + 2][col] = v.z;
    CpT[c0 + 3][col] = v.w;
    float4 s4 = *(const float4*)&Sin[sinbase + (size_t)r * 64 + c0];  // r = p
    SnT[c0 + 0][col] = s4.x;
    SnT[c0 + 1][col] = s4.y;
    SnT[c0 + 2][col] = s4.z;
    SnT[c0 + 3][col] = s4.w;
  }
  __syncthreads();
  float acc[4][4] = {};
#pragma unroll 8
  for (int n = 0; n < 64; ++n) {
    int rot = n & ~3;
    float4 cv = *(const float4*)&CpT[n][(ty * 4 + rot) & 63];
    float4 sv = *(const float4*)&SnT[n][(tx * 4 + rot) & 63];
    float ci[4] = {cv.x, cv.y, cv.z, cv.w};
    float pj[4] = {sv.x, sv.y, sv.z, sv.w};
#pragma unroll
    for (int i = 0; i < 4; ++i)
#pragma unroll
      for (int j = 0; j < 4; ++j) acc[i][j] += ci[i] * pj[j];
  }
  float Dh = Dskip[h];
#pragma unroll
  for (int i = 0; i < 4; ++i) {
    int t = tp * 64 + ty * 4 + i;
    float et = expf(sA[t]);
    size_t grow = (size_t)(rowbase + t);
    float4 xv = *(const float4*)&xbc[grow * 512 + h * 64 + tx * 4];
    float* yp = &y[grow * DI + h * 64 + tx * 4];
    float4 yv = *(const float4*)yp;
    yv.x += et * acc[i][0] + Dh * xv.x;
    yv.y += et * acc[i][1] + Dh * xv.y;
    yv.z += et * acc[i][2] + Dh * xv.z;
    yv.w += et * acc[i][3] + Dh * xv.w;
    *(float4*)yp = yv;
  }
}

// ---------------- K9: g = y*silu(z); RMSNorm(384) * ssm_norm_w -> gn
__global__ __launch_bounds__(128) void k_gate(const float* __restrict__ y,
    const float* __restrict__ zx, const float* __restrict__ nw, float* __restrict__ gn) {
  int row = blockIdx.x;
  int tid = threadIdx.x;
  float g[3]; float sq = 0.f;
#pragma unroll
  for (int i = 0; i < 3; ++i) {
    int d = tid + i * 128;
    float z = zx[(size_t)row * DIP + d];
    float gg = y[(size_t)row * DI + d] * (z / (1.f + expf(-z)));
    g[i] = gg; sq += gg * gg;
  }
  for (int off = 32; off > 0; off >>= 1) sq += __shfl_down(sq, off);
  __shared__ float wsum[2];
  if ((tid & 63) == 0) wsum[tid >> 6] = sq;
  __syncthreads();
  float rs = rsqrtf((wsum[0] + wsum[1]) / 384.f + 1e-5f);
#pragma unroll
  for (int i = 0; i < 3; ++i) {
    int d = tid + i * 128;
    gn[(size_t)row * DI + d] = g[i] * rs * nw[d];
  }
}

// ---------------- K11: resid[b,t,c] = x[b,c,t] + m[b,t,c]
__global__ void k_resid(const float* __restrict__ x, const float* __restrict__ m,
                        float* __restrict__ r) {
  __shared__ float s[32][33];
  int bb = blockIdx.z; int c0 = blockIdx.y * 32; int t0 = blockIdx.x * 32;
  int tx = threadIdx.x, ty = threadIdx.y;
  for (int i = 0; i < 4; ++i)
    s[ty + i * 8][tx] = x[((size_t)bb * CHN + c0 + ty + i * 8) * LEN + t0 + tx];
  __syncthreads();
  for (int i = 0; i < 4; ++i) {
    size_t o = ((size_t)bb * LEN + t0 + ty + i * 8) * CHN + c0 + tx;
    r[o] = s[tx][ty + i * 8] + m[o];
  }
}

// ---------------- K12: plain LayerNorm over 192 (rowwise)
__global__ __launch_bounds__(64) void k_ln2(const float* __restrict__ r,
    const float* __restrict__ w, const float* __restrict__ b, float* __restrict__ h2) {
  int row = blockIdx.x;
  int tid = threadIdx.x;
  float v[3]; float sum = 0.f;
#pragma unroll
  for (int i = 0; i < 3; ++i) { v[i] = r[(size_t)row * CHN + tid + i * 64]; sum += v[i]; }
  for (int off = 32; off > 0; off >>= 1) sum += __shfl_down(sum, off);
  sum = __shfl(sum, 0);
  float mu = sum / 192.f;
  float sq = 0.f;
#pragma unroll
  for (int i = 0; i < 3; ++i) { float d = v[i] - mu; sq += d * d; }
  for (int off = 32; off > 0; off >>= 1) sq += __shfl_down(sq, off);
  sq = __shfl(sq, 0);
  float rs = rsqrtf(sq / 192.f + 1e-5f);
#pragma unroll
  for (int i = 0; i < 3; ++i) {
    int c = tid + i * 64;
    h2[(size_t)row * CHN + c] = (v[i] - mu) * rs * w[c] + b[c];
  }
}

// ---------------- K15: out[b,c,t] = resid[b,t,c] + f2[b,t,c]  (f32 out)
__global__ void k_out(const float* __restrict__ r, const float* __restrict__ f,
                      float* __restrict__ out) {
  __shared__ float s[32][33];
  int bb = blockIdx.z; int c0 = blockIdx.y * 32; int t0 = blockIdx.x * 32;
  int tx = threadIdx.x, ty = threadIdx.y;
  for (int i = 0; i < 4; ++i) {
    size_t o = ((size_t)bb * LEN + t0 + ty + i * 8) * CHN + c0 + tx;
    s[tx][ty + i * 8] = r[o] + f[o];
  }
  __syncthreads();
  for (int i = 0; i < 4; ++i)
    out[((size_t)bb * CHN + c0 + ty + i * 8) * LEN + t0 + tx] = s[ty + i * 8][tx];
}

extern "C" void kernel_launch(void* const* d_in, const int* in_sizes, int n_in,
                              void* d_out, int out_size, void* d_ws, size_t ws_size,
                              hipStream_t stream) {
  const float* x     = (const float*)d_in[0];
  const float* n1w   = (const float*)d_in[1];
  const float* n1b   = (const float*)d_in[2];
  const float* win   = (const float*)d_in[3];
  const float* cw    = (const float*)d_in[4];
  const float* cb    = (const float*)d_in[5];
  const float* dtbw  = (const float*)d_in[6];
  const float* alog  = (const float*)d_in[7];
  const float* dskip = (const float*)d_in[8];
  const float* snw   = (const float*)d_in[9];
  const float* wout  = (const float*)d_in[10];
  const float* n2w   = (const float*)d_in[11];
  const float* n2b   = (const float*)d_in[12];
  const float* w1    = (const float*)d_in[13];
  const float* b1    = (const float*)d_in[14];
  const float* w2    = (const float*)d_in[15];
  const float* b2    = (const float*)d_in[16];
  float* out = (float*)d_out;

  int g = 4;
  for (;;) {
    size_t S_BLC = (size_t)g * LEN * CHN;
    size_t S_ZX  = (size_t)g * LEN * DIP;
    size_t S_DT  = (size_t)g * LEN * NHEAD;
    size_t S_XBC = (size_t)g * LEN * 512;
    size_t S_Y   = (size_t)g * LEN * DI;
    size_t S_ST  = (size_t)g * NCHK * NHEAD * 4096;
    size_t TOTAL = 2 * S_BLC + S_ZX + S_DT + S_XBC + S_Y + 2 * S_ST + 768;
    if (TOTAL * 4 <= ws_size) break;
    if (g == 1) return;
    g >>= 1;
  }

  const size_t S_BLC = (size_t)g * LEN * CHN;
  const size_t S_ZX  = (size_t)g * LEN * DIP;
  const size_t S_DT  = (size_t)g * LEN * NHEAD;
  const size_t S_XBC = (size_t)g * LEN * 512;
  const size_t S_Y   = (size_t)g * LEN * DI;
  const size_t S_ST  = (size_t)g * NCHK * NHEAD * 4096;

  float* ws   = (float*)d_ws;
  float* h1   = ws;
  float* U    = ws + S_BLC;
  float* gn   = ws;
  float* zx   = ws + 2 * S_BLC;
  float* h2   = zx;
  float* f1   = zx + S_BLC;
  float* f2   = zx + S_BLC + S_Y;
  float* dtb  = zx + S_ZX;
  float* xbc  = dtb + S_DT;
  float* m_   = xbc;
  float* resid= xbc + S_BLC;
  float* yb   = xbc + S_XBC;
  float* st   = yb + S_Y;
  float* si   = st + S_ST;
  float* at   = si + S_ST;

  const int M = g * LEN;

  for (int b0 = 0; b0 < BATCH; b0 += g) {
    const float* xg  = x   + (size_t)b0 * CHN * LEN;
    float*       og  = out + (size_t)b0 * CHN * LEN;

    k_ln1<<<dim3(LEN / 32, g), 256, 0, stream>>>(xg, n1w, n1b, h1);
    k_make_u<<<dim3(LEN / 32, CHN / 32, g), dim3(32, 8), 0, stream>>>(h1, U);
    gemm_mfma<0><<<dim3(896 / 64, M / 128), 256, 0, stream>>>(
        U, win, nullptr, zx, M, 896, CHN, DIP);
    k_dt2<<<dim3(M / 4), 256, 0, stream>>>(U, win, dtbw, dtb);
    k_conv<<<dim3((M * 512 + 255) / 256), 256, 0, stream>>>(zx, cw, cb, xbc, M * 512);
    // SSD intra-chunk (MFMA, merged per-chunk blocks)
    k_ssd1<<<dim3(NCHK, NHEAD, g), 256, 0, stream>>>(xbc, dtb, alog, yb, st, at);
    k_scan<<<dim3(NHEAD, g), 256, 0, stream>>>(st, at, si);
    k_ssd2<<<dim3(NCHK * 4, NHEAD, g), 256, 0, stream>>>(xbc, dtb, alog, dskip, si, yb);
    k_gate<<<dim3(M), 128, 0, stream>>>(yb, zx, snw, gn);
    gemm_mfma<0><<<dim3(CHN / 64, M / 128), 256, 0, stream>>>(
        gn, wout, nullptr, m_, M, CHN, DI, CHN);
    k_resid<<<dim3(LEN / 32, CHN / 32, g), dim3(32, 8), 0, stream>>>(xg, m_, resid);
    k_ln2<<<dim3(M), 64, 0, stream>>>(resid, n2w, n2b, h2);
    gemm_mfma<1><<<dim3(DI / 64, M / 128), 256, 0, stream>>>(
        h2, w1, b1, f1, M, DI, CHN, DI);
    gemm_mfma<2><<<dim3(CHN / 64, M / 128), 256, 0, stream>>>(
        f1, w2, b2, f2, M, CHN, DI, CHN);
    k_out<<<dim3(LEN / 32, CHN / 32, g), dim3(32, 8), 0, stream>>>(resid, f2, og);
  }
}

// Round 9
// 617.420 us; speedup vs baseline: 5.3377x; 1.0012x over previous
//
#include <hip/hip_runtime.h>
#include <hip/hip_bf16.h>

#define BATCH 8
#define CHN   192      // d_model
#define LEN   4096     // H*W tokens
#define DIP   902      // in_proj out dim
#define DI    384      // d_inner
#define NHEAD 6
#define HDIM  64
#define DST   64       // d_state
#define NCHK  16       // chunks (LEN/256)

typedef __attribute__((ext_vector_type(8))) short short8;
typedef __attribute__((ext_vector_type(4))) short short4v;
typedef __attribute__((ext_vector_type(4))) float f32x4;

__device__ __forceinline__ short f2b(float f) {
  unsigned u = __builtin_bit_cast(unsigned, f);
  unsigned r = (u + 0x7FFFu + ((u >> 16) & 1u)) >> 16;  // round-to-nearest-even
  return (short)r;
}

// ---------------- K1: transposing LayerNorm1: x (g,192,L) f32 -> h1 (g,L,192) f32
__global__ __launch_bounds__(256) void k_ln1(const float* __restrict__ x,
    const float* __restrict__ w, const float* __restrict__ b, float* __restrict__ h1) {
  __shared__ float s[192][33];
  __shared__ float red[2][32][8];
  __shared__ float mu_s[32], rs_s[32];
  int bb = blockIdx.y;
  int t0 = blockIdx.x * 32;
  int tid = threadIdx.x;
  for (int i = 0; i < 24; ++i) {
    int idx = tid + i * 256;            // 192*32 = 6144
    int c = idx >> 5, tt = idx & 31;
    s[c][tt] = x[((size_t)bb * CHN + c) * LEN + t0 + tt];
  }
  __syncthreads();
  int tok = tid & 31, part = tid >> 5;
  float sum = 0.f, sq = 0.f;
  for (int c = part * 24; c < part * 24 + 24; ++c) { float v = s[c][tok]; sum += v; sq += v * v; }
  red[0][tok][part] = sum; red[1][tok][part] = sq;
  __syncthreads();
  if (tid < 32) {
    float su = 0.f, qq = 0.f;
    for (int p = 0; p < 8; ++p) { su += red[0][tid][p]; qq += red[1][tid][p]; }
    float mu = su / 192.f;
    float var = qq / 192.f - mu * mu;
    mu_s[tid] = mu; rs_s[tid] = rsqrtf(var + 1e-5f);
  }
  __syncthreads();
  for (int i = 0; i < 24; ++i) {
    int idx = tid + i * 256;
    int c = idx % 192, tt = idx / 192;
    float v = (s[c][tt] - mu_s[tt]) * rs_s[tt] * w[c] + b[c];
    h1[((size_t)bb * LEN + t0 + tt) * CHN + c] = v;
  }
}

// ---------------- K2: u[b,l,c2] = h1_flat[b][c2*LEN + l]
__global__ void k_make_u(const float* __restrict__ h1, float* __restrict__ U) {
  __shared__ float s[32][33];
  int bb = blockIdx.z;
  int c0 = blockIdx.y * 32;
  int l0 = blockIdx.x * 32;
  int tx = threadIdx.x, ty = threadIdx.y;
  const float* src = h1 + (size_t)bb * (CHN * LEN);
  for (int i = 0; i < 4; ++i)
    s[ty + i * 8][tx] = src[(size_t)(c0 + ty + i * 8) * LEN + l0 + tx];
  __syncthreads();
  float* dst = U + (size_t)bb * (CHN * LEN);
  for (int i = 0; i < 4; ++i)
    dst[(size_t)(l0 + ty + i * 8) * CHN + c0 + tx] = s[tx][ty + i * 8];
}

// ---------------- MFMA GEMM: C = A(f32->bf16) @ W^T(f32->bf16), f32 out
// EPI 0: C ; 1: C=gelu(v+bias) ; 2: C=v+bias ; 3: fused final: v+bias+resid,
//        store TRANSPOSED to outT[(row>>12)*CHN+col][row&4095] (no C write)
template <int EPI>
__global__ __launch_bounds__(256) void gemm_mfma(const float* __restrict__ A,
    const float* __restrict__ W, const float* __restrict__ bias,
    float* __restrict__ C, int M, int N, int K, int ldc,
    const float* __restrict__ resid, float* __restrict__ outT) {
  __shared__ short Al[128 * 64];  // row stride 128 B
  __shared__ short Wl[64 * 64];
  int m0 = blockIdx.y * 128, n0 = blockIdx.x * 64;
  int tid = threadIdx.x;
  int lane = tid & 63, wv = tid >> 6;
  int wm = (wv >> 1) * 64, wn = (wv & 1) * 32;
  int l15 = lane & 15, l4 = lane >> 4;
  f32x4 acc[4][2] = {};

  int ra = tid >> 1, ca = (tid & 1) * 32;
  int rw = tid >> 2, cw = (tid & 3) * 16;
  char* ArowL = (char*)Al + ra * 128;
  char* WrowL = (char*)Wl + rw * 128;
  int rxa = (ra & 7) << 4, rxw = (rw & 7) << 4;

  for (int k0 = 0; k0 < K; k0 += 64) {
    const float* Ag = A + (size_t)(m0 + ra) * K + k0 + ca;
    const float* Wg = W + (size_t)(n0 + rw) * K + k0 + cw;
#pragma unroll
    for (int q = 0; q < 4; ++q) {
      float4 v0 = *(const float4*)(Ag + q * 8);
      float4 v1 = *(const float4*)(Ag + q * 8 + 4);
      short8 pk;
      pk[0] = f2b(v0.x); pk[1] = f2b(v0.y); pk[2] = f2b(v0.z); pk[3] = f2b(v0.w);
      pk[4] = f2b(v1.x); pk[5] = f2b(v1.y); pk[6] = f2b(v1.z); pk[7] = f2b(v1.w);
      *(short8*)(ArowL + (((ca + q * 8) * 2) ^ rxa)) = pk;
    }
#pragma unroll
    for (int q = 0; q < 2; ++q) {
      float4 v0 = *(const float4*)(Wg + q * 8);
      float4 v1 = *(const float4*)(Wg + q * 8 + 4);
      short8 pk;
      pk[0] = f2b(v0.x); pk[1] = f2b(v0.y); pk[2] = f2b(v0.z); pk[3] = f2b(v0.w);
      pk[4] = f2b(v1.x); pk[5] = f2b(v1.y); pk[6] = f2b(v1.z); pk[7] = f2b(v1.w);
      *(short8*)(WrowL + (((cw + q * 8) * 2) ^ rxw)) = pk;
    }
    __syncthreads();
#pragma unroll
    for (int ks = 0; ks < 64; ks += 32) {
      short8 af[4], wf[2];
#pragma unroll
      for (int mf = 0; mf < 4; ++mf) {
        int rr = wm + mf * 16 + l15;
        af[mf] = *(const short8*)((const char*)Al + rr * 128 +
                                  (((ks + l4 * 8) * 2) ^ ((rr & 7) << 4)));
      }
#pragma unroll
      for (int nf = 0; nf < 2; ++nf) {
        int rr = wn + nf * 16 + l15;
        wf[nf] = *(const short8*)((const char*)Wl + rr * 128 +
                                  (((ks + l4 * 8) * 2) ^ ((rr & 7) << 4)));
      }
#pragma unroll
      for (int mf = 0; mf < 4; ++mf)
#pragma unroll
        for (int nf = 0; nf < 2; ++nf)
          acc[mf][nf] = __builtin_amdgcn_mfma_f32_16x16x32_bf16(
              af[mf], wf[nf], acc[mf][nf], 0, 0, 0);
    }
    __syncthreads();
  }
#pragma unroll
  for (int mf = 0; mf < 4; ++mf) {
#pragma unroll
    for (int nf = 0; nf < 2; ++nf) {
      int col = n0 + wn + nf * 16 + l15;
      float bv = (EPI >= 1) ? bias[col] : 0.f;
      if (EPI == 3) {
        int row0 = m0 + wm + mf * 16 + l4 * 4;
        float4 o;
#pragma unroll
        for (int reg = 0; reg < 4; ++reg) {
          int row = row0 + reg;
          ((float*)&o)[reg] = acc[mf][nf][reg] + bv + resid[(size_t)row * CHN + col];
        }
        int bb_l = row0 >> 12, row_l = row0 & 4095;
        *(float4*)&outT[((size_t)bb_l * CHN + col) * LEN + row_l] = o;
      } else {
#pragma unroll
        for (int reg = 0; reg < 4; ++reg) {
          int row = m0 + wm + mf * 16 + l4 * 4 + reg;
          float v = acc[mf][nf][reg];
          if (EPI >= 1) v += bv;
          if (EPI == 1) v = 0.5f * v * (1.f + erff(v * 0.70710678118f));
          C[(size_t)row * ldc + col] = v;
        }
      }
    }
  }
}

// ---------------- K4: dt computed EXACTLY in f32 from U
__global__ __launch_bounds__(256) void k_dt2(const float* __restrict__ U,
    const float* __restrict__ win, const float* __restrict__ dt_bias,
    float* __restrict__ dtb) {
  __shared__ float Wl[6][192];
  int tid = threadIdx.x;
  for (int i = tid; i < 6 * 192; i += 256)
    Wl[i / 192][i % 192] = win[(size_t)(896 + i / 192) * 192 + (i % 192)];
  __syncthreads();
  int lane = tid & 63, wv = tid >> 6;
  int row = blockIdx.x * 4 + wv;
  float u0 = U[(size_t)row * 192 + lane];
  float u1 = U[(size_t)row * 192 + lane + 64];
  float u2 = U[(size_t)row * 192 + lane + 128];
  float acc[6];
#pragma unroll
  for (int h = 0; h < 6; ++h) {
    float p = u0 * Wl[h][lane] + u1 * Wl[h][lane + 64] + u2 * Wl[h][lane + 128];
    for (int off = 32; off > 0; off >>= 1) p += __shfl_down(p, off);
    acc[h] = p;
  }
  if (lane == 0) {
#pragma unroll
    for (int h = 0; h < 6; ++h) {
      float v = acc[h] + dt_bias[h];
      dtb[(size_t)row * NHEAD + h] = (v > 20.f) ? v : log1pf(expf(v));
    }
  }
}

// ---------------- K5: causal depthwise conv(4) + bias + silu -> xbc (g,L,512)
__global__ void k_conv(const float* __restrict__ zx, const float* __restrict__ cw,
                       const float* __restrict__ cb, float* __restrict__ xbc, int total) {
  int idx = blockIdx.x * 256 + threadIdx.x;
  if (idx >= total) return;
  int ch = idx & 511; int l = (idx >> 9) & (LEN - 1); int bb = idx >> 21;
  float acc = cb[ch];
#pragma unroll
  for (int k = 0; k < 4; ++k) {
    int ll = l - 3 + k;
    if (ll >= 0) acc += zx[((size_t)bb * LEN + ll) * DIP + 384 + ch] * cw[ch * 4 + k];
  }
  xbc[idx] = acc / (1.f + expf(-acc));
}

// ---------------- K5b: per-(chunk,head) inclusive cumsum of dt*A -> sAg
// per-wave shfl scan, no barriers. block = (cch, bb); wave wv handles h = wv, wv+4.
__global__ __launch_bounds__(256) void k_cumsum(const float* __restrict__ dtb,
    const float* __restrict__ A_log, float* __restrict__ sAg) {
  int cch = blockIdx.x, bb = blockIdx.y;
  int lane = threadIdx.x & 63, wv = threadIdx.x >> 6;
  size_t rowbase = (size_t)bb * LEN + cch * 256;
  for (int h = wv; h < NHEAD; h += 4) {
    float Ah = -expf(A_log[h]);
    float v[4];
#pragma unroll
    for (int i = 0; i < 4; ++i)
      v[i] = dtb[(rowbase + lane * 4 + i) * NHEAD + h] * Ah;
    v[1] += v[0]; v[2] += v[1]; v[3] += v[2];
    float tot = v[3];
    float sc = tot;
    for (int off = 1; off < 64; off <<= 1) {
      float o = __shfl_up(sc, off);
      if (lane >= off) sc += o;
    }
    float excl = sc - tot;
#pragma unroll
    for (int i = 0; i < 4; ++i)
      sAg[(rowbase + lane * 4 + i) * NHEAD + h] = v[i] + excl;
  }
}

// ---------------- K6: SSD intra-chunk MFMA, split per t-panel, cooperative waves.
// block = (cch*4+tp, h, bb); 4 waves share each (tp,st) tile pair.
// LDS 42KB: Ct/Bt/Xt/St/BeT 64x64 bf16 tiles + sA/sE.
__global__ __launch_bounds__(256) void k_ssd1(const float* __restrict__ xbc,
    const float* __restrict__ sAg, const float* __restrict__ dtb,
    float* __restrict__ y, float* __restrict__ states) {
  int q = blockIdx.x;
  int cch = q >> 2, tp = q & 3;
  int h = blockIdx.y, bb = blockIdx.z;
  int tid = threadIdx.x;
  int lane = tid & 63, wv = tid >> 6;
  int l15 = lane & 15, l4 = lane >> 4;
  __shared__ float sA[256];
  __shared__ float sE[256];
  __shared__ short Ct[64 * 64];   // [t_loc][n]
  __shared__ short Bt[64 * 64];   // [s_loc][n]
  __shared__ short Xt[64 * 64];   // [p][s_loc]
  __shared__ short St[64 * 64];   // [t_loc][s_loc]
  __shared__ short BeT[64 * 64];  // [n][s_loc] (tp==3 only)
  size_t rowbase = (size_t)bb * LEN + cch * 256;
  sA[tid] = sAg[(rowbase + tid) * NHEAD + h];
  __syncthreads();
  if (tp == 3) sE[tid] = __expf(sA[255] - sA[tid]);
  // stage Ct for this tp
  {
    int r = tid >> 2, cq = (tid & 3) * 16;
    size_t grow = (size_t)(rowbase + tp * 64 + r) * 512;
    int swr = (r & 7) << 4;
#pragma unroll
    for (int qq = 0; qq < 4; ++qq) {
      int c0 = cq + qq * 4;
      float4 cv = *(const float4*)&xbc[grow + 448 + c0];
      short4v cp = {f2b(cv.x), f2b(cv.y), f2b(cv.z), f2b(cv.w)};
      *(short4v*)((char*)Ct + r * 128 + ((c0 * 2) ^ swr)) = cp;
    }
  }
  f32x4 yacc[4] = {};
  f32x4 stacc[4] = {};
  for (int st = 0; st <= tp; ++st) {
    __syncthreads();  // prev tiles consumed; Ct/sE staged (1st iter)
    {
      int r = tid >> 2, cq = (tid & 3) * 16;
      size_t grow = (size_t)(rowbase + st * 64 + r) * 512;
      float dtv = dtb[(rowbase + st * 64 + r) * NHEAD + h];
      int swr = (r & 7) << 4;
      float e = (tp == 3) ? sE[st * 64 + r] : 0.f;
#pragma unroll
      for (int qq = 0; qq < 4; ++qq) {
        int c0 = cq + qq * 4;
        float4 bv = *(const float4*)&xbc[grow + 384 + c0];
        short4v bp = {f2b(bv.x), f2b(bv.y), f2b(bv.z), f2b(bv.w)};
        *(short4v*)((char*)Bt + r * 128 + ((c0 * 2) ^ swr)) = bp;
        float4 xv = *(const float4*)&xbc[grow + h * 64 + c0];
#pragma unroll
        for (int j = 0; j < 4; ++j) {
          int p = c0 + j;
          *(short*)((char*)Xt + p * 128 + ((r * 2) ^ ((p & 7) << 4))) =
              f2b(((const float*)&xv)[j] * dtv);
          if (tp == 3)
            *(short*)((char*)BeT + p * 128 + ((r * 2) ^ ((p & 7) << 4))) =
                f2b(((const float*)&bv)[j] * e);
        }
      }
    }
    __syncthreads();
    // phase 1: S tile, wave wv owns s-rows wv*16..+15, all 4 t-tiles
    f32x4 p1[4] = {};
#pragma unroll
    for (int ks = 0; ks < 2; ++ks) {
      int rs = wv * 16 + l15;
      short8 a = *(const short8*)((const char*)Bt + rs * 128 +
                                  (((ks * 32 + l4 * 8) * 2) ^ ((rs & 7) << 4)));
#pragma unroll
      for (int ni = 0; ni < 4; ++ni) {
        int rt = ni * 16 + l15;
        short8 b = *(const short8*)((const char*)Ct + rt * 128 +
                                    (((ks * 32 + l4 * 8) * 2) ^ ((rt & 7) << 4)));
        p1[ni] = __builtin_amdgcn_mfma_f32_16x16x32_bf16(a, b, p1[ni], 0, 0, 0);
      }
    }
    // mask + decay -> St[t][s]
    {
      int s_base = st * 64 + wv * 16 + l4 * 4;
      float sAs[4];
#pragma unroll
      for (int reg = 0; reg < 4; ++reg) sAs[reg] = sA[s_base + reg];
#pragma unroll
      for (int ni = 0; ni < 4; ++ni) {
        int t_loc = ni * 16 + l15;
        int tg = tp * 64 + t_loc;
        float At = sA[tg];
        short4v pk;
#pragma unroll
        for (int reg = 0; reg < 4; ++reg) {
          float v = (s_base + reg <= tg) ? __expf(At - sAs[reg]) * p1[ni][reg] : 0.f;
          pk[reg] = f2b(v);
        }
        *(short4v*)((char*)St + t_loc * 128 +
                    (((wv * 16 + l4 * 4) * 2) ^ ((t_loc & 7) << 4))) = pk;
      }
    }
    __syncthreads();
    // phase 2: Y += Xt @ St^T ; wave wv owns t-tile wv (n), 4 p-tiles (m)
#pragma unroll
    for (int ks = 0; ks < 2; ++ks) {
      int rt = wv * 16 + l15;
      short8 bS = *(const short8*)((const char*)St + rt * 128 +
                                   (((ks * 32 + l4 * 8) * 2) ^ ((rt & 7) << 4)));
#pragma unroll
      for (int mi = 0; mi < 4; ++mi) {
        int rp = mi * 16 + l15;
        short8 aX = *(const short8*)((const char*)Xt + rp * 128 +
                                     (((ks * 32 + l4 * 8) * 2) ^ ((rp & 7) << 4)));
        yacc[mi] = __builtin_amdgcn_mfma_f32_16x16x32_bf16(aX, bS, yacc[mi], 0, 0, 0);
      }
    }
    // phase 3 (tp==3): states += BeT @ Xt^T ; wave wv owns n-rows wv*16..+15
    if (tp == 3) {
#pragma unroll
      for (int ks = 0; ks < 2; ++ks) {
        int rn = wv * 16 + l15;
        short8 aB = *(const short8*)((const char*)BeT + rn * 128 +
                                     (((ks * 32 + l4 * 8) * 2) ^ ((rn & 7) << 4)));
#pragma unroll
        for (int ni = 0; ni < 4; ++ni) {
          int rp = ni * 16 + l15;
          short8 bX = *(const short8*)((const char*)Xt + rp * 128 +
                                       (((ks * 32 + l4 * 8) * 2) ^ ((rp & 7) << 4)));
          stacc[ni] = __builtin_amdgcn_mfma_f32_16x16x32_bf16(aB, bX, stacc[ni], 0, 0, 0);
        }
      }
    }
  }
  // write Y panel: t = tp*64 + wv*16 + l15 ; p = mi*16 + l4*4 + reg
  {
    int tg = tp * 64 + wv * 16 + l15;
#pragma unroll
    for (int mi = 0; mi < 4; ++mi) {
      float4 o = {yacc[mi][0], yacc[mi][1], yacc[mi][2], yacc[mi][3]};
      *(float4*)&y[(rowbase + tg) * DI + h * 64 + mi * 16 + l4 * 4] = o;
    }
  }
  if (tp == 3) {
    size_t stbase = (((size_t)bb * NCHK + cch) * NHEAD + h) * 4096;
#pragma unroll
    for (int ni = 0; ni < 4; ++ni) {
      int p = ni * 16 + l15;
      float4 o = {stacc[ni][0], stacc[ni][1], stacc[ni][2], stacc[ni][3]};
      *(float4*)&states[stbase + p * 64 + wv * 16 + l4 * 4] = o;
    }
  }
}

// ---------------- K7: inter-chunk scan (sequential over 16 chunks)
__global__ void k_scan(const float* __restrict__ states, const float* __restrict__ sAg,
                       float* __restrict__ Sin) {
  int h = blockIdx.x, bb = blockIdx.y;
  int t = threadIdx.x;
  float S[16];
#pragma unroll
  for (int i = 0; i < 16; ++i) S[i] = 0.f;
  for (int z = 0; z < NCHK; ++z) {
    size_t base = (((size_t)bb * NCHK + z) * NHEAD + h) * 4096 + t * 16;
#pragma unroll
    for (int i = 0; i < 16; ++i) Sin[base + i] = S[i];
    float az = __expf(sAg[((size_t)bb * LEN + z * 256 + 255) * NHEAD + h]);
#pragma unroll
    for (int i = 0; i < 16; ++i) S[i] = S[i] * az + states[base + i];
  }
}

// ---------------- K8: y += Y_off + xs*D_skip  (register-tiled, per t-panel)
__global__ __launch_bounds__(256) void k_ssd2(const float* __restrict__ xbc,
    const float* __restrict__ sAg, const float* __restrict__ A_log,
    const float* __restrict__ Dskip, const float* __restrict__ Sin, float* __restrict__ y) {
  int cchq = blockIdx.x;
  int cch = cchq >> 2, tp = cchq & 3;
  int h = blockIdx.y, bb = blockIdx.z;
  int tid = threadIdx.x;
  int tx = tid & 15, ty = tid >> 4;
  __shared__ float sA[256];
  __shared__ float CpT[64][68];   // [n][t'] rotated
  __shared__ float SnT[64][68];   // [n][p'] rotated
  size_t rowbase = (size_t)bb * LEN + cch * 256;
  sA[tid] = sAg[(rowbase + tid) * NHEAD + h];
  size_t sinbase = (((size_t)bb * NCHK + cch) * NHEAD + h) * 4096;
#pragma unroll
  for (int i = 0; i < 4; ++i) {
    int idx = tid + i * 256;
    int r = idx >> 4, c0 = (idx & 15) * 4;
    int col = (r + c0) & 63;
    float4 v = *(const float4*)&xbc[(rowbase + tp * 64 + r) * 512 + 448 + c0];
    CpT[c0 + 0][col] = v.x;
    CpT[c0 + 1][col] = v.y;
    CpT[c0 + 2][col] = v.z;
    CpT[c0 + 3][col] = v.w;
    float4 s4 = *(const float4*)&Sin[sinbase + (size_t)r * 64 + c0];  // r = p
    SnT[c0 + 0][col] = s4.x;
    SnT[c0 + 1][col] = s4.y;
    SnT[c0 + 2][col] = s4.z;
    SnT[c0 + 3][col] = s4.w;
  }
  __syncthreads();
  float acc[4][4] = {};
#pragma unroll 8
  for (int n = 0; n < 64; ++n) {
    int rot = n & ~3;
    float4 cv = *(const float4*)&CpT[n][(ty * 4 + rot) & 63];
    float4 sv = *(const float4*)&SnT[n][(tx * 4 + rot) & 63];
    float ci[4] = {cv.x, cv.y, cv.z, cv.w};
    float pj[4] = {sv.x, sv.y, sv.z, sv.w};
#pragma unroll
    for (int i = 0; i < 4; ++i)
#pragma unroll
      for (int j = 0; j < 4; ++j) acc[i][j] += ci[i] * pj[j];
  }
  float Dh = Dskip[h];
#pragma unroll
  for (int i = 0; i < 4; ++i) {
    int t = tp * 64 + ty * 4 + i;
    float et = __expf(sA[t]);
    size_t grow = (size_t)(rowbase + t);
    float4 xv = *(const float4*)&xbc[grow * 512 + h * 64 + tx * 4];
    float* yp = &y[grow * DI + h * 64 + tx * 4];
    float4 yv = *(const float4*)yp;
    yv.x += et * acc[i][0] + Dh * xv.x;
    yv.y += et * acc[i][1] + Dh * xv.y;
    yv.z += et * acc[i][2] + Dh * xv.z;
    yv.w += et * acc[i][3] + Dh * xv.w;
    *(float4*)yp = yv;
  }
}

// ---------------- K9: g = y*silu(z); RMSNorm(384) * ssm_norm_w -> gn
__global__ __launch_bounds__(128) void k_gate(const float* __restrict__ y,
    const float* __restrict__ zx, const float* __restrict__ nw, float* __restrict__ gn) {
  int row = blockIdx.x;
  int tid = threadIdx.x;
  float g[3]; float sq = 0.f;
#pragma unroll
  for (int i = 0; i < 3; ++i) {
    int d = tid + i * 128;
    float z = zx[(size_t)row * DIP + d];
    float gg = y[(size_t)row * DI + d] * (z / (1.f + expf(-z)));
    g[i] = gg; sq += gg * gg;
  }
  for (int off = 32; off > 0; off >>= 1) sq += __shfl_down(sq, off);
  __shared__ float wsum[2];
  if ((tid & 63) == 0) wsum[tid >> 6] = sq;
  __syncthreads();
  float rs = rsqrtf((wsum[0] + wsum[1]) / 384.f + 1e-5f);
#pragma unroll
  for (int i = 0; i < 3; ++i) {
    int d = tid + i * 128;
    gn[(size_t)row * DI + d] = g[i] * rs * nw[d];
  }
}

// ---------------- K11: resid[b,t,c] = x[b,c,t] + m[b,t,c]
__global__ void k_resid(const float* __restrict__ x, const float* __restrict__ m,
                        float* __restrict__ r) {
  __shared__ float s[32][33];
  int bb = blockIdx.z; int c0 = blockIdx.y * 32; int t0 = blockIdx.x * 32;
  int tx = threadIdx.x, ty = threadIdx.y;
  for (int i = 0; i < 4; ++i)
    s[ty + i * 8][tx] = x[((size_t)bb * CHN + c0 + ty + i * 8) * LEN + t0 + tx];
  __syncthreads();
  for (int i = 0; i < 4; ++i) {
    size_t o = ((size_t)bb * LEN + t0 + ty + i * 8) * CHN + c0 + tx;
    r[o] = s[tx][ty + i * 8] + m[o];
  }
}

// ---------------- K12: plain LayerNorm over 192 (rowwise)
__global__ __launch_bounds__(64) void k_ln2(const float* __restrict__ r,
    const float* __restrict__ w, const float* __restrict__ b, float* __restrict__ h2) {
  int row = blockIdx.x;
  int tid = threadIdx.x;
  float v[3]; float sum = 0.f;
#pragma unroll
  for (int i = 0; i < 3; ++i) { v[i] = r[(size_t)row * CHN + tid + i * 64]; sum += v[i]; }
  for (int off = 32; off > 0; off >>= 1) sum += __shfl_down(sum, off);
  sum = __shfl(sum, 0);
  float mu = sum / 192.f;
  float sq = 0.f;
#pragma unroll
  for (int i = 0; i < 3; ++i) { float d = v[i] - mu; sq += d * d; }
  for (int off = 32; off > 0; off >>= 1) sq += __shfl_down(sq, off);
  sq = __shfl(sq, 0);
  float rs = rsqrtf(sq / 192.f + 1e-5f);
#pragma unroll
  for (int i = 0; i < 3; ++i) {
    int c = tid + i * 64;
    h2[(size_t)row * CHN + c] = (v[i] - mu) * rs * w[c] + b[c];
  }
}

extern "C" void kernel_launch(void* const* d_in, const int* in_sizes, int n_in,
                              void* d_out, int out_size, void* d_ws, size_t ws_size,
                              hipStream_t stream) {
  const float* x     = (const float*)d_in[0];
  const float* n1w   = (const float*)d_in[1];
  const float* n1b   = (const float*)d_in[2];
  const float* win   = (const float*)d_in[3];
  const float* cw    = (const float*)d_in[4];
  const float* cb    = (const float*)d_in[5];
  const float* dtbw  = (const float*)d_in[6];
  const float* alog  = (const float*)d_in[7];
  const float* dskip = (const float*)d_in[8];
  const float* snw   = (const float*)d_in[9];
  const float* wout  = (const float*)d_in[10];
  const float* n2w   = (const float*)d_in[11];
  const float* n2b   = (const float*)d_in[12];
  const float* w1    = (const float*)d_in[13];
  const float* b1    = (const float*)d_in[14];
  const float* w2    = (const float*)d_in[15];
  const float* b2    = (const float*)d_in[16];
  float* out = (float*)d_out;

  int g = 4;
  for (;;) {
    size_t S_BLC = (size_t)g * LEN * CHN;
    size_t S_ZX  = (size_t)g * LEN * DIP;
    size_t S_DT  = (size_t)g * LEN * NHEAD;
    size_t S_XBC = (size_t)g * LEN * 512;
    size_t S_Y   = (size_t)g * LEN * DI;
    size_t S_ST  = (size_t)g * NCHK * NHEAD * 4096;
    size_t TOTAL = 2 * S_BLC + S_ZX + 2 * S_DT + S_XBC + S_Y + 2 * S_ST;
    if (TOTAL * 4 <= ws_size) break;
    if (g == 1) return;
    g >>= 1;
  }

  const size_t S_BLC = (size_t)g * LEN * CHN;
  const size_t S_ZX  = (size_t)g * LEN * DIP;
  const size_t S_DT  = (size_t)g * LEN * NHEAD;
  const size_t S_XBC = (size_t)g * LEN * 512;
  const size_t S_Y   = (size_t)g * LEN * DI;
  const size_t S_ST  = (size_t)g * NCHK * NHEAD * 4096;

  float* ws   = (float*)d_ws;
  float* h1   = ws;
  float* U    = ws + S_BLC;
  float* gn   = ws;
  float* zx   = ws + 2 * S_BLC;
  float* h2   = zx;
  float* f1   = zx + S_BLC;
  float* dtb  = zx + S_ZX;
  float* xbc  = dtb + S_DT;
  float* m_   = xbc;
  float* resid= xbc + S_BLC;
  float* yb   = xbc + S_XBC;
  float* st   = yb + S_Y;
  float* si   = st + S_ST;
  float* sag  = si + S_ST;

  const int M = g * LEN;

  for (int b0 = 0; b0 < BATCH; b0 += g) {
    const float* xg  = x   + (size_t)b0 * CHN * LEN;
    float*       og  = out + (size_t)b0 * CHN * LEN;

    k_ln1<<<dim3(LEN / 32, g), 256, 0, stream>>>(xg, n1w, n1b, h1);
    k_make_u<<<dim3(LEN / 32, CHN / 32, g), dim3(32, 8), 0, stream>>>(h1, U);
    gemm_mfma<0><<<dim3(896 / 64, M / 128), 256, 0, stream>>>(
        U, win, nullptr, zx, M, 896, CHN, DIP, nullptr, nullptr);
    k_dt2<<<dim3(M / 4), 256, 0, stream>>>(U, win, dtbw, dtb);
    k_conv<<<dim3((M * 512 + 255) / 256), 256, 0, stream>>>(zx, cw, cb, xbc, M * 512);
    k_cumsum<<<dim3(NCHK, g), 256, 0, stream>>>(dtb, alog, sag);
    k_ssd1<<<dim3(NCHK * 4, NHEAD, g), 256, 0, stream>>>(xbc, sag, dtb, yb, st);
    k_scan<<<dim3(NHEAD, g), 256, 0, stream>>>(st, sag, si);
    k_ssd2<<<dim3(NCHK * 4, NHEAD, g), 256, 0, stream>>>(xbc, sag, alog, dskip, si, yb);
    k_gate<<<dim3(M), 128, 0, stream>>>(yb, zx, snw, gn);
    gemm_mfma<0><<<dim3(CHN / 64, M / 128), 256, 0, stream>>>(
        gn, wout, nullptr, m_, M, CHN, DI, CHN, nullptr, nullptr);
    k_resid<<<dim3(LEN / 32, CHN / 32, g), dim3(32, 8), 0, stream>>>(xg, m_, resid);
    k_ln2<<<dim3(M), 64, 0, stream>>>(resid, n2w, n2b, h2);
    gemm_mfma<1><<<dim3(DI / 64, M / 128), 256, 0, stream>>>(
        h2, w1, b1, f1, M, DI, CHN, DI, nullptr, nullptr);
    // FFN2 fused: +bias +resid, transposed f32 store to out
    gemm_mfma<3><<<dim3(CHN / 64, M / 128), 256, 0, stream>>>(
        f1, w2, b2, nullptr, M, CHN, DI, CHN, resid, og);
  }
}